// Round 1
// baseline (10538.822 us; speedup 1.0000x reference)
//
#include <hip/hip_runtime.h>
#include <hip/hip_bf16.h>
#include <math.h>

// GPT-2 small forward: B=2, S=1024, V=50257, D=768, H=12, L=6, F=3072, DK=64
#define BB 2
#define SS 1024
#define DD 768
#define HH 12
#define LL 6
#define FF 3072
#define VV 50257
#define DKK 64
#define NROWS (BB * SS)   // 2048

__device__ __forceinline__ float gelu_f(float x) {
    // exact GELU: 0.5*x*(1+erf(x/sqrt(2)))
    return 0.5f * x * (1.0f + erff(x * 0.70710678118654752440f));
}

// ---------------- embedding: x[b,s,:] = tok[ids[b,s],:] + pos[s,:] ----------------
__global__ __launch_bounds__(256) void embed_kernel(
    const int* __restrict__ ids, const float* __restrict__ tok,
    const float* __restrict__ pos, float* __restrict__ x) {
    int row = blockIdx.x;              // b*S + s
    int s = row & (SS - 1);
    int id = ids[row];
    const float* t = tok + (size_t)id * DD;
    const float* p = pos + (size_t)s * DD;
    float* xr = x + (size_t)row * DD;
    for (int i = threadIdx.x; i < DD; i += 256)
        xr[i] = t[i] + p[i];
}

// ---------------- layernorm over D=768, one block per row ----------------
__global__ __launch_bounds__(256) void ln_kernel(
    const float* __restrict__ x, const float* __restrict__ g,
    const float* __restrict__ b, float* __restrict__ out) {
    int row = blockIdx.x;
    int tid = threadIdx.x;
    const float* xr = x + (size_t)row * DD;
    float v0 = xr[tid], v1 = xr[tid + 256], v2 = xr[tid + 512];
    __shared__ float red[256];
    red[tid] = v0 + v1 + v2;
    __syncthreads();
    for (int s2 = 128; s2 > 0; s2 >>= 1) {
        if (tid < s2) red[tid] += red[tid + s2];
        __syncthreads();
    }
    float mu = red[0] * (1.0f / DD);
    __syncthreads();
    float d0 = v0 - mu, d1 = v1 - mu, d2 = v2 - mu;
    red[tid] = d0 * d0 + d1 * d1 + d2 * d2;
    __syncthreads();
    for (int s2 = 128; s2 > 0; s2 >>= 1) {
        if (tid < s2) red[tid] += red[tid + s2];
        __syncthreads();
    }
    float r = rsqrtf(red[0] * (1.0f / DD) + 1e-5f);
    float* o = out + (size_t)row * DD;
    o[tid]       = d0 * r * g[tid]       + b[tid];
    o[tid + 256] = d1 * r * g[tid + 256] + b[tid + 256];
    o[tid + 512] = d2 * r * g[tid + 512] + b[tid + 512];
}

// ---------------- generic fused GEMM: C = epilogue(A @ W) ----------------
// A: [M,K] row-major, W: [K,N] row-major. BM=BN=64, BK=16, 256 threads, 4x4/thread.
// epilogue: (+bias[col]), (GELU), (+residual[row,col]). N bounds-checked.
__global__ __launch_bounds__(256) void gemm_kernel(
    const float* __restrict__ A, const float* __restrict__ W,
    const float* __restrict__ bias, const float* __restrict__ residual,
    float* __restrict__ C, int M, int N, int K, int do_gelu) {
    __shared__ float As[16][64];   // [k][m]
    __shared__ float Ws[16][68];   // [k][n], pad 4 to spread banks
    int tid = threadIdx.x;
    int bn = blockIdx.x * 64, bm = blockIdx.y * 64;
    int tx = tid & 15, ty = tid >> 4;
    int ar = tid >> 2, ak = (tid & 3) << 2;     // A tile: 64 rows x 4 float4
    int wr = tid >> 4, wc = (tid & 15) << 2;    // W tile: 16 rows x 16 float4
    bool n_vec = ((N & 3) == 0);                // float4-safe W rows?
    float acc[4][4] = {};

    for (int k0 = 0; k0 < K; k0 += 16) {
        // stage A (K is always a multiple of 16, M a multiple of 64)
        float4 av = *(const float4*)&A[(size_t)(bm + ar) * K + (k0 + ak)];
        As[ak + 0][ar] = av.x; As[ak + 1][ar] = av.y;
        As[ak + 2][ar] = av.z; As[ak + 3][ar] = av.w;
        // stage W (guard N edge; scalar loads when rows are not 16B-aligned)
        int gn = bn + wc;
        const float* wp = &W[(size_t)(k0 + wr) * N + gn];
        float w0, w1, w2, w3;
        if (n_vec && gn + 3 < N) {
            float4 wv4 = *(const float4*)wp;
            w0 = wv4.x; w1 = wv4.y; w2 = wv4.z; w3 = wv4.w;
        } else {
            w0 = (gn + 0 < N) ? wp[0] : 0.0f;
            w1 = (gn + 1 < N) ? wp[1] : 0.0f;
            w2 = (gn + 2 < N) ? wp[2] : 0.0f;
            w3 = (gn + 3 < N) ? wp[3] : 0.0f;
        }
        Ws[wr][wc + 0] = w0; Ws[wr][wc + 1] = w1;
        Ws[wr][wc + 2] = w2; Ws[wr][wc + 3] = w3;
        __syncthreads();
#pragma unroll
        for (int kk = 0; kk < 16; ++kk) {
            float a[4], w[4];
#pragma unroll
            for (int i = 0; i < 4; ++i) a[i] = As[kk][ty * 4 + i];
#pragma unroll
            for (int j = 0; j < 4; ++j) w[j] = Ws[kk][tx * 4 + j];
#pragma unroll
            for (int i = 0; i < 4; ++i)
#pragma unroll
                for (int j = 0; j < 4; ++j)
                    acc[i][j] = fmaf(a[i], w[j], acc[i][j]);
        }
        __syncthreads();
    }

#pragma unroll
    for (int i = 0; i < 4; ++i) {
        int row = bm + ty * 4 + i;
#pragma unroll
        for (int j = 0; j < 4; ++j) {
            int col = bn + tx * 4 + j;
            if (col < N) {
                float val = acc[i][j];
                if (bias) val += bias[col];
                if (do_gelu) val = gelu_f(val);
                if (residual) val += residual[(size_t)row * N + col];
                C[(size_t)row * N + col] = val;
            }
        }
    }
}

// ---------------- causal attention, one block per (b,h,qi) ----------------
// q,k,v laid out [B*S, D] with head h at columns [h*DK, (h+1)*DK)
__global__ __launch_bounds__(256) void attn_kernel(
    const float* __restrict__ q, const float* __restrict__ k,
    const float* __restrict__ v, float* __restrict__ ctx) {
    int bid = blockIdx.x;              // (b*H + h)*S + qi
    int qi = bid & (SS - 1);
    int bh = bid >> 10;                // b*H + h
    int h = bh % HH;
    int b = bh / HH;
    int tid = threadIdx.x;

    __shared__ float qs[DKK];
    __shared__ float p[SS];
    __shared__ float red[256];
    __shared__ float ctx_red[4][DKK];

    const float* qrow = q + ((size_t)(b * SS + qi)) * DD + h * DKK;
    if (tid < DKK) qs[tid] = qrow[tid];
    __syncthreads();

    int nk = qi + 1;                   // causal: ki <= qi
    const float scale = 0.125f;        // 1/sqrt(64)

    for (int ki = tid; ki < nk; ki += 256) {
        const float* krow = k + ((size_t)(b * SS + ki)) * DD + h * DKK;
        float dot = 0.0f;
#pragma unroll
        for (int d = 0; d < DKK; d += 4) {
            float4 kv = *(const float4*)&krow[d];
            dot += qs[d] * kv.x + qs[d + 1] * kv.y + qs[d + 2] * kv.z + qs[d + 3] * kv.w;
        }
        p[ki] = dot * scale;
    }
    __syncthreads();

    // row max
    float lmax = -1e30f;
    for (int ki = tid; ki < nk; ki += 256) lmax = fmaxf(lmax, p[ki]);
    red[tid] = lmax;
    __syncthreads();
    for (int s2 = 128; s2 > 0; s2 >>= 1) {
        if (tid < s2) red[tid] = fmaxf(red[tid], red[tid + s2]);
        __syncthreads();
    }
    float m = red[0];
    __syncthreads();

    // exp + sum (each thread owns the same ki's it wrote -> no p hazard)
    float lsum = 0.0f;
    for (int ki = tid; ki < nk; ki += 256) {
        float e = __expf(p[ki] - m);
        p[ki] = e;
        lsum += e;
    }
    red[tid] = lsum;
    __syncthreads();
    for (int s2 = 128; s2 > 0; s2 >>= 1) {
        if (tid < s2) red[tid] += red[tid + s2];
        __syncthreads();
    }
    float inv = 1.0f / red[0];

    // ctx[d] = inv * sum_ki p[ki] * v[ki,d]; wave w handles ki = w mod 4
    int d = tid & 63;
    int chunk = tid >> 6;
    float accd = 0.0f;
    for (int ki = chunk; ki < nk; ki += 4)
        accd += p[ki] * v[((size_t)(b * SS + ki)) * DD + h * DKK + d];
    ctx_red[chunk][d] = accd;
    __syncthreads();
    if (tid < DKK) {
        float sum = (ctx_red[0][tid] + ctx_red[1][tid]) + (ctx_red[2][tid] + ctx_red[3][tid]);
        ctx[((size_t)(b * SS + qi)) * DD + h * DKK + tid] = sum * inv;
    }
}

// ---------------- host-side orchestration ----------------
extern "C" void kernel_launch(void* const* d_in, const int* in_sizes, int n_in,
                              void* d_out, int out_size, void* d_ws, size_t ws_size,
                              hipStream_t stream) {
    const int*   ids    = (const int*)  d_in[0];
    const float* tok    = (const float*)d_in[1];
    const float* pos    = (const float*)d_in[2];
    const float* wq     = (const float*)d_in[3];
    const float* wk     = (const float*)d_in[4];
    const float* wv     = (const float*)d_in[5];
    const float* wo     = (const float*)d_in[6];
    const float* bo     = (const float*)d_in[7];
    const float* fc_w   = (const float*)d_in[8];
    const float* fc_b   = (const float*)d_in[9];
    const float* proj_w = (const float*)d_in[10];
    const float* proj_b = (const float*)d_in[11];
    const float* ln1_g  = (const float*)d_in[12];
    const float* ln1_b  = (const float*)d_in[13];
    const float* ln2_g  = (const float*)d_in[14];
    const float* ln2_b  = (const float*)d_in[15];
    const float* lnf_g  = (const float*)d_in[16];
    const float* lnf_b  = (const float*)d_in[17];
    const float* out_w  = (const float*)d_in[18];
    float* out = (float*)d_out;

    const size_t XSZ = (size_t)NROWS * DD;   // 1572864 floats
    float* ws = (float*)d_ws;
    float* x  = ws;
    float* xn = x  + XSZ;
    float* qb = xn + XSZ;
    float* kb = qb + XSZ;
    float* vb = kb + XSZ;
    float* cb = vb + XSZ;
    float* hb = cb + XSZ;                    // [NROWS, F] = 6291456 floats

    dim3 blk(256);
    dim3 gD((DD + 63) / 64, NROWS / 64);     // N=768  -> 12 x 32
    dim3 gF((FF + 63) / 64, NROWS / 64);     // N=3072 -> 48 x 32
    dim3 gV((VV + 63) / 64, NROWS / 64);     // N=50257-> 786 x 32

    embed_kernel<<<NROWS, blk, 0, stream>>>(ids, tok, pos, x);

    for (int l = 0; l < LL; ++l) {
        const float* wq_l = wq + (size_t)l * DD * DD;
        const float* wk_l = wk + (size_t)l * DD * DD;
        const float* wv_l = wv + (size_t)l * DD * DD;
        const float* wo_l = wo + (size_t)l * DD * DD;
        const float* fc_w_l = fc_w + (size_t)l * DD * FF;
        const float* pj_w_l = proj_w + (size_t)l * FF * DD;

        ln_kernel<<<NROWS, blk, 0, stream>>>(x, ln1_g + l * DD, ln1_b + l * DD, xn);
        gemm_kernel<<<gD, blk, 0, stream>>>(xn, wq_l, nullptr, nullptr, qb, NROWS, DD, DD, 0);
        gemm_kernel<<<gD, blk, 0, stream>>>(xn, wk_l, nullptr, nullptr, kb, NROWS, DD, DD, 0);
        gemm_kernel<<<gD, blk, 0, stream>>>(xn, wv_l, nullptr, nullptr, vb, NROWS, DD, DD, 0);
        attn_kernel<<<BB * HH * SS, blk, 0, stream>>>(qb, kb, vb, cb);
        // x = x + ctx @ wo + bo   (in-place: each elem read+written by its own thread)
        gemm_kernel<<<gD, blk, 0, stream>>>(cb, wo_l, bo + l * DD, x, x, NROWS, DD, DD, 0);
        ln_kernel<<<NROWS, blk, 0, stream>>>(x, ln2_g + l * DD, ln2_b + l * DD, xn);
        gemm_kernel<<<gF, blk, 0, stream>>>(xn, fc_w_l, fc_b + l * FF, nullptr, hb, NROWS, FF, DD, 1);
        gemm_kernel<<<gD, blk, 0, stream>>>(hb, pj_w_l, proj_b + l * DD, x, x, NROWS, DD, FF, 0);
    }

    ln_kernel<<<NROWS, blk, 0, stream>>>(x, lnf_g, lnf_b, xn);
    gemm_kernel<<<gV, blk, 0, stream>>>(xn, out_w, nullptr, nullptr, out, NROWS, VV, DD, 0);
}

// Round 2
// 5368.062 us; speedup vs baseline: 1.9632x; 1.9632x over previous
//
#include <hip/hip_runtime.h>
#include <hip/hip_bf16.h>
#include <math.h>

// GPT-2 small forward: B=2, S=1024, V=50257, D=768, H=12, L=6, F=3072, DK=64
#define BB 2
#define SS 1024
#define DD 768
#define HH 12
#define LL 6
#define FF 3072
#define VV 50257
#define DKK 64
#define NROWS (BB * SS)   // 2048
#define QKVN (3 * DD)     // 2304

typedef __attribute__((ext_vector_type(8))) short short8v;  // 8 bf16 = 4 VGPRs
typedef __attribute__((ext_vector_type(4))) float f32x4;
typedef __attribute__((ext_vector_type(4))) int int4v;

__device__ __forceinline__ float gelu_f(float x) {
    return 0.5f * x * (1.0f + erff(x * 0.70710678118654752440f));
}

// ---------------- embedding ----------------
__global__ __launch_bounds__(256) void embed_kernel(
    const int* __restrict__ ids, const float* __restrict__ tok,
    const float* __restrict__ pos, float* __restrict__ x) {
    int row = blockIdx.x;
    int s = row & (SS - 1);
    int id = ids[row];
    const float* t = tok + (size_t)id * DD;
    const float* p = pos + (size_t)s * DD;
    float* xr = x + (size_t)row * DD;
    for (int i = threadIdx.x; i < DD; i += 256)
        xr[i] = t[i] + p[i];
}

// ---------------- layernorm (fp32 in, fp32 out) — fallback path ----------------
__global__ __launch_bounds__(256) void ln_kernel(
    const float* __restrict__ x, const float* __restrict__ g,
    const float* __restrict__ b, float* __restrict__ out) {
    int row = blockIdx.x;
    int tid = threadIdx.x;
    const float* xr = x + (size_t)row * DD;
    float v0 = xr[tid], v1 = xr[tid + 256], v2 = xr[tid + 512];
    __shared__ float red[256];
    red[tid] = v0 + v1 + v2;
    __syncthreads();
    for (int s2 = 128; s2 > 0; s2 >>= 1) {
        if (tid < s2) red[tid] += red[tid + s2];
        __syncthreads();
    }
    float mu = red[0] * (1.0f / DD);
    __syncthreads();
    float d0 = v0 - mu, d1 = v1 - mu, d2 = v2 - mu;
    red[tid] = d0 * d0 + d1 * d1 + d2 * d2;
    __syncthreads();
    for (int s2 = 128; s2 > 0; s2 >>= 1) {
        if (tid < s2) red[tid] += red[tid + s2];
        __syncthreads();
    }
    float r = rsqrtf(red[0] * (1.0f / DD) + 1e-5f);
    float* o = out + (size_t)row * DD;
    o[tid]       = d0 * r * g[tid]       + b[tid];
    o[tid + 256] = d1 * r * g[tid + 256] + b[tid + 256];
    o[tid + 512] = d2 * r * g[tid + 512] + b[tid + 512];
}

// ---------------- layernorm (fp32 in, bf16 out) — MFMA path ----------------
__global__ __launch_bounds__(256) void ln_bf16_kernel(
    const float* __restrict__ x, const float* __restrict__ g,
    const float* __restrict__ b, __hip_bfloat16* __restrict__ out) {
    int row = blockIdx.x;
    int tid = threadIdx.x;
    const float* xr = x + (size_t)row * DD;
    float v0 = xr[tid], v1 = xr[tid + 256], v2 = xr[tid + 512];
    __shared__ float red[256];
    red[tid] = v0 + v1 + v2;
    __syncthreads();
    for (int s2 = 128; s2 > 0; s2 >>= 1) {
        if (tid < s2) red[tid] += red[tid + s2];
        __syncthreads();
    }
    float mu = red[0] * (1.0f / DD);
    __syncthreads();
    float d0 = v0 - mu, d1 = v1 - mu, d2 = v2 - mu;
    red[tid] = d0 * d0 + d1 * d1 + d2 * d2;
    __syncthreads();
    for (int s2 = 128; s2 > 0; s2 >>= 1) {
        if (tid < s2) red[tid] += red[tid + s2];
        __syncthreads();
    }
    float r = rsqrtf(red[0] * (1.0f / DD) + 1e-5f);
    __hip_bfloat16* o = out + (size_t)row * DD;
    o[tid]       = __float2bfloat16(d0 * r * g[tid]       + b[tid]);
    o[tid + 256] = __float2bfloat16(d1 * r * g[tid + 256] + b[tid + 256]);
    o[tid + 512] = __float2bfloat16(d2 * r * g[tid + 512] + b[tid + 512]);
}

// ---------------- W [K,N] f32  ->  Wt [N,K] bf16 ----------------
__global__ __launch_bounds__(256) void transpose_cvt_kernel(
    const float* __restrict__ W, __hip_bfloat16* __restrict__ Wt, int K, int N) {
    __shared__ float t[32][33];
    int bn = blockIdx.x * 32, bk = blockIdx.y * 32;
    int tx = threadIdx.x & 31, ty = threadIdx.x >> 5;
    for (int r = ty; r < 32; r += 8)
        t[r][tx] = (bn + tx < N) ? W[(size_t)(bk + r) * N + bn + tx] : 0.0f;
    __syncthreads();
    for (int r = ty; r < 32; r += 8) {
        int n = bn + r;
        if (n < N) Wt[(size_t)n * K + bk + tx] = __float2bfloat16(t[tx][r]);
    }
}

// ---------------- bf16 MFMA GEMM: C = epilogue(A @ Wt^T) ----------------
// A [M,K] bf16 row-major; Wt [N,K] bf16 row-major. BK=32, 256 thr = 4 waves.
// Wave grid 2x2; each wave computes (BM/2)x(BN/2) via 16x16x32 MFMA frags.
// LDS rows are 64B (32 bf16); 16B slots XOR-swizzled by ((row>>1)&3).
#define LDSOFF(row, ks) (((row) * 64) + ((((ks) ^ (((row) >> 1) & 3))) << 4))

template<int BM, int BN>
__global__ __launch_bounds__(256) void gemm_mfma_kernel(
    const __hip_bfloat16* __restrict__ A, const __hip_bfloat16* __restrict__ Wt,
    const float* __restrict__ bias, const float* __restrict__ residual,
    float* __restrict__ Cf, __hip_bfloat16* __restrict__ Cb,
    int M, int N, int K, int do_gelu) {
    constexpr int BK = 32;
    constexpr int UA = (BM * 4) / 256;  // 16B chunks per thread for A tile
    constexpr int UB = (BN * 4) / 256;
    constexpr int FM = BM / 32;         // frags per wave (M dir)
    constexpr int FN = BN / 32;
    __shared__ __align__(16) char As[BM * 64];
    __shared__ __align__(16) char Bs[BN * 64];

    const int tid = threadIdx.x;
    const int lane = tid & 63;
    const int wid = tid >> 6;
    const int bm = blockIdx.y * BM;
    const int bn = blockIdx.x * BN;
    const int r16 = lane & 15;
    const int kg = lane >> 4;               // k-group: k = kg*8
    const int wm = (wid >> 1) * (FM * 16);
    const int wn = (wid & 1) * (FN * 16);

    f32x4 acc[FM][FN];
    const f32x4 zf = {0.0f, 0.0f, 0.0f, 0.0f};
#pragma unroll
    for (int i = 0; i < FM; ++i)
#pragma unroll
        for (int j = 0; j < FN; ++j) acc[i][j] = zf;

    int4v areg[UA], breg[UB];
    const int4v zi = {0, 0, 0, 0};

#pragma unroll
    for (int u = 0; u < UA; ++u) {
        int c = tid + u * 256, row = c >> 2, sl = c & 3;
        areg[u] = *(const int4v*)(A + (size_t)(bm + row) * K + sl * 8);
    }
#pragma unroll
    for (int u = 0; u < UB; ++u) {
        int c = tid + u * 256, row = c >> 2, sl = c & 3;
        int4v bv = zi;
        if (bn + row < N) bv = *(const int4v*)(Wt + (size_t)(bn + row) * K + sl * 8);
        breg[u] = bv;
    }

    for (int k0 = 0; k0 < K; k0 += BK) {
        __syncthreads();   // previous compute's LDS reads done
#pragma unroll
        for (int u = 0; u < UA; ++u) {
            int c = tid + u * 256, row = c >> 2, sl = c & 3;
            *(int4v*)(As + LDSOFF(row, sl)) = areg[u];
        }
#pragma unroll
        for (int u = 0; u < UB; ++u) {
            int c = tid + u * 256, row = c >> 2, sl = c & 3;
            *(int4v*)(Bs + LDSOFF(row, sl)) = breg[u];
        }
        __syncthreads();
        int kn = k0 + BK;
        if (kn < K) {      // prefetch next tile into regs; hides under MFMA
#pragma unroll
            for (int u = 0; u < UA; ++u) {
                int c = tid + u * 256, row = c >> 2, sl = c & 3;
                areg[u] = *(const int4v*)(A + (size_t)(bm + row) * K + kn + sl * 8);
            }
#pragma unroll
            for (int u = 0; u < UB; ++u) {
                int c = tid + u * 256, row = c >> 2, sl = c & 3;
                int4v bv = zi;
                if (bn + row < N) bv = *(const int4v*)(Wt + (size_t)(bn + row) * K + kn + sl * 8);
                breg[u] = bv;
            }
        }
        short8v af[FM], bfr[FN];
#pragma unroll
        for (int i = 0; i < FM; ++i) {
            int row = wm + i * 16 + r16;
            af[i] = *(const short8v*)(As + LDSOFF(row, kg));
        }
#pragma unroll
        for (int j = 0; j < FN; ++j) {
            int row = wn + j * 16 + r16;
            bfr[j] = *(const short8v*)(Bs + LDSOFF(row, kg));
        }
#pragma unroll
        for (int i = 0; i < FM; ++i)
#pragma unroll
            for (int j = 0; j < FN; ++j)
                acc[i][j] = __builtin_amdgcn_mfma_f32_16x16x32_bf16(
                    af[i], bfr[j], acc[i][j], 0, 0, 0);
    }

    // C/D layout: col = lane&15, row = (lane>>4)*4 + reg  [m89-verified]
    const int rg = lane >> 4;
#pragma unroll
    for (int i = 0; i < FM; ++i) {
#pragma unroll
        for (int j = 0; j < FN; ++j) {
            int col = bn + wn + j * 16 + r16;
            if (col < N) {
#pragma unroll
                for (int r = 0; r < 4; ++r) {
                    int row = bm + wm + i * 16 + rg * 4 + r;
                    float v = acc[i][j][r];
                    if (bias) v += bias[col];
                    if (do_gelu) v = gelu_f(v);
                    size_t o = (size_t)row * N + col;
                    if (residual) v += residual[o];
                    if (Cf) Cf[o] = v;
                    else Cb[o] = __float2bfloat16(v);
                }
            }
        }
    }
}

// ---------------- old fp32 GEMM (fallback path) ----------------
__global__ __launch_bounds__(256) void gemm_kernel(
    const float* __restrict__ A, const float* __restrict__ W,
    const float* __restrict__ bias, const float* __restrict__ residual,
    float* __restrict__ C, int M, int N, int K, int do_gelu) {
    __shared__ float As[16][64];
    __shared__ float Ws[16][68];
    int tid = threadIdx.x;
    int bn = blockIdx.x * 64, bm = blockIdx.y * 64;
    int tx = tid & 15, ty = tid >> 4;
    int ar = tid >> 2, ak = (tid & 3) << 2;
    int wr = tid >> 4, wc = (tid & 15) << 2;
    bool n_vec = ((N & 3) == 0);
    float acc[4][4] = {};
    for (int k0 = 0; k0 < K; k0 += 16) {
        float4 av = *(const float4*)&A[(size_t)(bm + ar) * K + (k0 + ak)];
        As[ak + 0][ar] = av.x; As[ak + 1][ar] = av.y;
        As[ak + 2][ar] = av.z; As[ak + 3][ar] = av.w;
        int gn = bn + wc;
        const float* wp = &W[(size_t)(k0 + wr) * N + gn];
        float w0, w1, w2, w3;
        if (n_vec && gn + 3 < N) {
            float4 wv4 = *(const float4*)wp;
            w0 = wv4.x; w1 = wv4.y; w2 = wv4.z; w3 = wv4.w;
        } else {
            w0 = (gn + 0 < N) ? wp[0] : 0.0f;
            w1 = (gn + 1 < N) ? wp[1] : 0.0f;
            w2 = (gn + 2 < N) ? wp[2] : 0.0f;
            w3 = (gn + 3 < N) ? wp[3] : 0.0f;
        }
        Ws[wr][wc + 0] = w0; Ws[wr][wc + 1] = w1;
        Ws[wr][wc + 2] = w2; Ws[wr][wc + 3] = w3;
        __syncthreads();
#pragma unroll
        for (int kk = 0; kk < 16; ++kk) {
            float a[4], w[4];
#pragma unroll
            for (int i = 0; i < 4; ++i) a[i] = As[kk][ty * 4 + i];
#pragma unroll
            for (int j = 0; j < 4; ++j) w[j] = Ws[kk][tx * 4 + j];
#pragma unroll
            for (int i = 0; i < 4; ++i)
#pragma unroll
                for (int j = 0; j < 4; ++j)
                    acc[i][j] = fmaf(a[i], w[j], acc[i][j]);
        }
        __syncthreads();
    }
#pragma unroll
    for (int i = 0; i < 4; ++i) {
        int row = bm + ty * 4 + i;
#pragma unroll
        for (int j = 0; j < 4; ++j) {
            int col = bn + tx * 4 + j;
            if (col < N) {
                float val = acc[i][j];
                if (bias) val += bias[col];
                if (do_gelu) val = gelu_f(val);
                if (residual) val += residual[(size_t)row * N + col];
                C[(size_t)row * N + col] = val;
            }
        }
    }
}

// ---------------- attention on fused QKV [M, 3D] f32, ctx out bf16 ----------------
__global__ __launch_bounds__(256) void attn_fused_kernel(
    const float* __restrict__ qkv, __hip_bfloat16* __restrict__ ctx) {
    int bid = blockIdx.x;
    int qi = bid & (SS - 1);
    int bh = bid >> 10;
    int h = bh % HH;
    int b = bh / HH;
    int tid = threadIdx.x;

    __shared__ float qs[DKK];
    __shared__ float p[SS];
    __shared__ float red[256];
    __shared__ float ctx_red[4][DKK];

    const float* qrow = qkv + (size_t)(b * SS + qi) * QKVN + h * DKK;
    if (tid < DKK) qs[tid] = qrow[tid];
    __syncthreads();

    int nk = qi + 1;
    const float scale = 0.125f;

    for (int ki = tid; ki < nk; ki += 256) {
        const float* krow = qkv + (size_t)(b * SS + ki) * QKVN + DD + h * DKK;
        float dot = 0.0f;
#pragma unroll
        for (int d = 0; d < DKK; d += 4) {
            float4 kv = *(const float4*)&krow[d];
            dot += qs[d] * kv.x + qs[d + 1] * kv.y + qs[d + 2] * kv.z + qs[d + 3] * kv.w;
        }
        p[ki] = dot * scale;
    }
    __syncthreads();

    float lmax = -1e30f;
    for (int ki = tid; ki < nk; ki += 256) lmax = fmaxf(lmax, p[ki]);
    red[tid] = lmax;
    __syncthreads();
    for (int s2 = 128; s2 > 0; s2 >>= 1) {
        if (tid < s2) red[tid] = fmaxf(red[tid], red[tid + s2]);
        __syncthreads();
    }
    float m = red[0];
    __syncthreads();

    float lsum = 0.0f;
    for (int ki = tid; ki < nk; ki += 256) {
        float e = __expf(p[ki] - m);
        p[ki] = e;
        lsum += e;
    }
    red[tid] = lsum;
    __syncthreads();
    for (int s2 = 128; s2 > 0; s2 >>= 1) {
        if (tid < s2) red[tid] += red[tid + s2];
        __syncthreads();
    }
    float inv = 1.0f / red[0];

    int d = tid & 63;
    int chunk = tid >> 6;
    float accd = 0.0f;
    for (int ki = chunk; ki < nk; ki += 4)
        accd += p[ki] * qkv[(size_t)(b * SS + ki) * QKVN + 2 * DD + h * DKK + d];
    ctx_red[chunk][d] = accd;
    __syncthreads();
    if (tid < DKK) {
        float sum = (ctx_red[0][tid] + ctx_red[1][tid]) + (ctx_red[2][tid] + ctx_red[3][tid]);
        ctx[(size_t)(b * SS + qi) * DD + h * DKK + tid] = __float2bfloat16(sum * inv);
    }
}

// ---------------- old fp32 attention (fallback path) ----------------
__global__ __launch_bounds__(256) void attn_kernel(
    const float* __restrict__ q, const float* __restrict__ k,
    const float* __restrict__ v, float* __restrict__ ctx) {
    int bid = blockIdx.x;
    int qi = bid & (SS - 1);
    int bh = bid >> 10;
    int h = bh % HH;
    int b = bh / HH;
    int tid = threadIdx.x;
    __shared__ float qs[DKK];
    __shared__ float p[SS];
    __shared__ float red[256];
    __shared__ float ctx_red[4][DKK];
    const float* qrow = q + ((size_t)(b * SS + qi)) * DD + h * DKK;
    if (tid < DKK) qs[tid] = qrow[tid];
    __syncthreads();
    int nk = qi + 1;
    const float scale = 0.125f;
    for (int ki = tid; ki < nk; ki += 256) {
        const float* krow = k + ((size_t)(b * SS + ki)) * DD + h * DKK;
        float dot = 0.0f;
#pragma unroll
        for (int d = 0; d < DKK; d += 4) {
            float4 kv = *(const float4*)&krow[d];
            dot += qs[d] * kv.x + qs[d + 1] * kv.y + qs[d + 2] * kv.z + qs[d + 3] * kv.w;
        }
        p[ki] = dot * scale;
    }
    __syncthreads();
    float lmax = -1e30f;
    for (int ki = tid; ki < nk; ki += 256) lmax = fmaxf(lmax, p[ki]);
    red[tid] = lmax;
    __syncthreads();
    for (int s2 = 128; s2 > 0; s2 >>= 1) {
        if (tid < s2) red[tid] = fmaxf(red[tid], red[tid + s2]);
        __syncthreads();
    }
    float m = red[0];
    __syncthreads();
    float lsum = 0.0f;
    for (int ki = tid; ki < nk; ki += 256) {
        float e = __expf(p[ki] - m);
        p[ki] = e;
        lsum += e;
    }
    red[tid] = lsum;
    __syncthreads();
    for (int s2 = 128; s2 > 0; s2 >>= 1) {
        if (tid < s2) red[tid] += red[tid + s2];
        __syncthreads();
    }
    float inv = 1.0f / red[0];
    int d = tid & 63;
    int chunk = tid >> 6;
    float accd = 0.0f;
    for (int ki = chunk; ki < nk; ki += 4)
        accd += p[ki] * v[((size_t)(b * SS + ki)) * DD + h * DKK + d];
    ctx_red[chunk][d] = accd;
    __syncthreads();
    if (tid < DKK) {
        float sum = (ctx_red[0][tid] + ctx_red[1][tid]) + (ctx_red[2][tid] + ctx_red[3][tid]);
        ctx[((size_t)(b * SS + qi)) * DD + h * DKK + tid] = sum * inv;
    }
}

// ---------------- host-side orchestration ----------------
extern "C" void kernel_launch(void* const* d_in, const int* in_sizes, int n_in,
                              void* d_out, int out_size, void* d_ws, size_t ws_size,
                              hipStream_t stream) {
    const int*   ids    = (const int*)  d_in[0];
    const float* tok    = (const float*)d_in[1];
    const float* pos    = (const float*)d_in[2];
    const float* wq     = (const float*)d_in[3];
    const float* wk     = (const float*)d_in[4];
    const float* wv     = (const float*)d_in[5];
    const float* wo     = (const float*)d_in[6];
    const float* bo     = (const float*)d_in[7];
    const float* fc_w   = (const float*)d_in[8];
    const float* fc_b   = (const float*)d_in[9];
    const float* proj_w = (const float*)d_in[10];
    const float* proj_b = (const float*)d_in[11];
    const float* ln1_g  = (const float*)d_in[12];
    const float* ln1_b  = (const float*)d_in[13];
    const float* ln2_g  = (const float*)d_in[14];
    const float* ln2_b  = (const float*)d_in[15];
    const float* lnf_g  = (const float*)d_in[16];
    const float* lnf_b  = (const float*)d_in[17];
    const float* out_w  = (const float*)d_in[18];
    float* out = (float*)d_out;

    dim3 blk(256);

    // ---- MFMA path ws layout ----
    const size_t SZ_X   = (size_t)NROWS * DD * 4;      //  6.29 MB fp32 residual
    const size_t SZ_XN  = (size_t)NROWS * DD * 2;      //  3.15 MB bf16 ln out
    const size_t SZ_QKV = (size_t)NROWS * QKVN * 4;    // 18.87 MB fp32 fused qkv
    const size_t SZ_CTX = (size_t)NROWS * DD * 2;      //  3.15 MB bf16 ctx
    const size_t SZ_H   = (size_t)NROWS * FF * 2;      // 12.58 MB bf16 mlp hidden
    const size_t SZ_WT  = (size_t)50304 * DD * 2;      // 77.27 MB bf16 W^T (reused)
    const size_t NEED   = SZ_X + SZ_XN + SZ_QKV + SZ_CTX + SZ_H + SZ_WT;

    if (ws_size >= NEED) {
        char* p = (char*)d_ws;
        float*          x    = (float*)p;          p += SZ_X;
        __hip_bfloat16* xn   = (__hip_bfloat16*)p; p += SZ_XN;
        float*          qkv  = (float*)p;          p += SZ_QKV;
        __hip_bfloat16* ctx  = (__hip_bfloat16*)p; p += SZ_CTX;
        __hip_bfloat16* hbuf = (__hip_bfloat16*)p; p += SZ_H;
        __hip_bfloat16* Wt   = (__hip_bfloat16*)p;

        dim3 tD(DD / 32, DD / 32);            // 768x768 transpose: 24x24
        dim3 tF(FF / 32, DD / 32);            // fc  W[768,3072]: 96x24
        dim3 tP(DD / 32, FF / 32);            // proj W[3072,768]: 24x96
        dim3 tV((VV + 31) / 32, DD / 32);     // out_w[768,50257]: 1571x24

        dim3 gQKV(QKVN / 128, NROWS / 128);   // 18 x 16
        dim3 gFC(FF / 128, NROWS / 128);      // 24 x 16
        dim3 gWO(DD / 64, NROWS / 64);        // 12 x 32
        dim3 gV((VV + 127) / 128, NROWS / 128); // 393 x 16

        embed_kernel<<<NROWS, blk, 0, stream>>>(ids, tok, pos, x);

        for (int l = 0; l < LL; ++l) {
            const float* wq_l = wq + (size_t)l * DD * DD;
            const float* wk_l = wk + (size_t)l * DD * DD;
            const float* wv_l = wv + (size_t)l * DD * DD;
            const float* wo_l = wo + (size_t)l * DD * DD;
            const float* fc_w_l = fc_w + (size_t)l * DD * FF;
            const float* pj_w_l = proj_w + (size_t)l * FF * DD;

            ln_bf16_kernel<<<NROWS, blk, 0, stream>>>(x, ln1_g + l * DD, ln1_b + l * DD, xn);
            transpose_cvt_kernel<<<tD, blk, 0, stream>>>(wq_l, Wt, DD, DD);
            transpose_cvt_kernel<<<tD, blk, 0, stream>>>(wk_l, Wt + (size_t)DD * DD, DD, DD);
            transpose_cvt_kernel<<<tD, blk, 0, stream>>>(wv_l, Wt + (size_t)2 * DD * DD, DD, DD);
            gemm_mfma_kernel<128, 128><<<gQKV, blk, 0, stream>>>(
                xn, Wt, nullptr, nullptr, qkv, nullptr, NROWS, QKVN, DD, 0);
            attn_fused_kernel<<<BB * HH * SS, blk, 0, stream>>>(qkv, ctx);
            transpose_cvt_kernel<<<tD, blk, 0, stream>>>(wo_l, Wt, DD, DD);
            gemm_mfma_kernel<64, 64><<<gWO, blk, 0, stream>>>(
                ctx, Wt, bo + l * DD, x, x, nullptr, NROWS, DD, DD, 0);
            ln_bf16_kernel<<<NROWS, blk, 0, stream>>>(x, ln2_g + l * DD, ln2_b + l * DD, xn);
            transpose_cvt_kernel<<<tF, blk, 0, stream>>>(fc_w_l, Wt, DD, FF);
            gemm_mfma_kernel<128, 128><<<gFC, blk, 0, stream>>>(
                xn, Wt, fc_b + l * FF, nullptr, nullptr, hbuf, NROWS, FF, DD, 1);
            transpose_cvt_kernel<<<tP, blk, 0, stream>>>(pj_w_l, Wt, FF, DD);
            gemm_mfma_kernel<64, 64><<<gWO, blk, 0, stream>>>(
                hbuf, Wt, proj_b + l * DD, x, x, nullptr, NROWS, DD, FF, 0);
        }

        ln_bf16_kernel<<<NROWS, blk, 0, stream>>>(x, lnf_g, lnf_b, xn);
        transpose_cvt_kernel<<<tV, blk, 0, stream>>>(out_w, Wt, DD, VV);
        gemm_mfma_kernel<128, 128><<<gV, blk, 0, stream>>>(
            xn, Wt, nullptr, nullptr, out, nullptr, NROWS, VV, DD, 0);
        return;
    }

    // ---- fallback: proven fp32 path (round-1 code) ----
    const size_t XSZ = (size_t)NROWS * DD;
    float* ws = (float*)d_ws;
    float* x  = ws;
    float* xn = x  + XSZ;
    float* qb = xn + XSZ;
    float* kb = qb + XSZ;
    float* vb = kb + XSZ;
    float* cb = vb + XSZ;
    float* hb = cb + XSZ;

    dim3 gD((DD + 63) / 64, NROWS / 64);
    dim3 gF((FF + 63) / 64, NROWS / 64);
    dim3 gV2((VV + 63) / 64, NROWS / 64);

    embed_kernel<<<NROWS, blk, 0, stream>>>(ids, tok, pos, x);
    for (int l = 0; l < LL; ++l) {
        const float* wq_l = wq + (size_t)l * DD * DD;
        const float* wk_l = wk + (size_t)l * DD * DD;
        const float* wv_l = wv + (size_t)l * DD * DD;
        const float* wo_l = wo + (size_t)l * DD * DD;
        const float* fc_w_l = fc_w + (size_t)l * DD * FF;
        const float* pj_w_l = proj_w + (size_t)l * FF * DD;
        ln_kernel<<<NROWS, blk, 0, stream>>>(x, ln1_g + l * DD, ln1_b + l * DD, xn);
        gemm_kernel<<<gD, blk, 0, stream>>>(xn, wq_l, nullptr, nullptr, qb, NROWS, DD, DD, 0);
        gemm_kernel<<<gD, blk, 0, stream>>>(xn, wk_l, nullptr, nullptr, kb, NROWS, DD, DD, 0);
        gemm_kernel<<<gD, blk, 0, stream>>>(xn, wv_l, nullptr, nullptr, vb, NROWS, DD, DD, 0);
        attn_kernel<<<BB * HH * SS, blk, 0, stream>>>(qb, kb, vb, cb);
        gemm_kernel<<<gD, blk, 0, stream>>>(cb, wo_l, bo + l * DD, x, x, NROWS, DD, DD, 0);
        ln_kernel<<<NROWS, blk, 0, stream>>>(x, ln2_g + l * DD, ln2_b + l * DD, xn);
        gemm_kernel<<<gF, blk, 0, stream>>>(xn, fc_w_l, fc_b + l * FF, nullptr, hb, NROWS, FF, DD, 1);
        gemm_kernel<<<gD, blk, 0, stream>>>(hb, pj_w_l, proj_b + l * DD, x, x, NROWS, DD, FF, 0);
    }
    ln_kernel<<<NROWS, blk, 0, stream>>>(x, lnf_g, lnf_b, xn);
    gemm_kernel<<<gV2, blk, 0, stream>>>(xn, out_w, nullptr, nullptr, out, NROWS, VV, DD, 0);
}

// Round 3
// 1572.932 us; speedup vs baseline: 6.7001x; 3.4128x over previous
//
#include <hip/hip_runtime.h>
#include <hip/hip_bf16.h>
#include <math.h>

// GPT-2 small forward: B=2, S=1024, V=50257, D=768, H=12, L=6, F=3072, DK=64
#define BB 2
#define SS 1024
#define DD 768
#define HH 12
#define LL 6
#define FF 3072
#define VV 50257
#define DKK 64
#define NROWS (BB * SS)   // 2048
#define QKVN (3 * DD)     // 2304
#define QBLK 64
#define KVBLK 64

typedef __attribute__((ext_vector_type(8))) short short8v;  // 8 bf16 = 4 VGPRs
typedef __attribute__((ext_vector_type(4))) float f32x4;
typedef __attribute__((ext_vector_type(4))) int int4v;

__device__ __forceinline__ float gelu_f(float x) {
    return 0.5f * x * (1.0f + erff(x * 0.70710678118654752440f));
}

// ---------------- embedding ----------------
__global__ __launch_bounds__(256) void embed_kernel(
    const int* __restrict__ ids, const float* __restrict__ tok,
    const float* __restrict__ pos, float* __restrict__ x) {
    int row = blockIdx.x;
    int s = row & (SS - 1);
    int id = ids[row];
    const float* t = tok + (size_t)id * DD;
    const float* p = pos + (size_t)s * DD;
    float* xr = x + (size_t)row * DD;
    for (int i = threadIdx.x; i < DD; i += 256)
        xr[i] = t[i] + p[i];
}

// ---------------- layernorm (fp32 in, fp32 out) — fallback ----------------
__global__ __launch_bounds__(256) void ln_kernel(
    const float* __restrict__ x, const float* __restrict__ g,
    const float* __restrict__ b, float* __restrict__ out) {
    int row = blockIdx.x;
    int tid = threadIdx.x;
    const float* xr = x + (size_t)row * DD;
    float v0 = xr[tid], v1 = xr[tid + 256], v2 = xr[tid + 512];
    __shared__ float red[256];
    red[tid] = v0 + v1 + v2;
    __syncthreads();
    for (int s2 = 128; s2 > 0; s2 >>= 1) {
        if (tid < s2) red[tid] += red[tid + s2];
        __syncthreads();
    }
    float mu = red[0] * (1.0f / DD);
    __syncthreads();
    float d0 = v0 - mu, d1 = v1 - mu, d2 = v2 - mu;
    red[tid] = d0 * d0 + d1 * d1 + d2 * d2;
    __syncthreads();
    for (int s2 = 128; s2 > 0; s2 >>= 1) {
        if (tid < s2) red[tid] += red[tid + s2];
        __syncthreads();
    }
    float r = rsqrtf(red[0] * (1.0f / DD) + 1e-5f);
    float* o = out + (size_t)row * DD;
    o[tid]       = d0 * r * g[tid]       + b[tid];
    o[tid + 256] = d1 * r * g[tid + 256] + b[tid + 256];
    o[tid + 512] = d2 * r * g[tid + 512] + b[tid + 512];
}

// ---------------- layernorm (fp32 in, bf16 out) ----------------
__global__ __launch_bounds__(256) void ln_bf16_kernel(
    const float* __restrict__ x, const float* __restrict__ g,
    const float* __restrict__ b, __hip_bfloat16* __restrict__ out) {
    int row = blockIdx.x;
    int tid = threadIdx.x;
    const float* xr = x + (size_t)row * DD;
    float v0 = xr[tid], v1 = xr[tid + 256], v2 = xr[tid + 512];
    __shared__ float red[256];
    red[tid] = v0 + v1 + v2;
    __syncthreads();
    for (int s2 = 128; s2 > 0; s2 >>= 1) {
        if (tid < s2) red[tid] += red[tid + s2];
        __syncthreads();
    }
    float mu = red[0] * (1.0f / DD);
    __syncthreads();
    float d0 = v0 - mu, d1 = v1 - mu, d2 = v2 - mu;
    red[tid] = d0 * d0 + d1 * d1 + d2 * d2;
    __syncthreads();
    for (int s2 = 128; s2 > 0; s2 >>= 1) {
        if (tid < s2) red[tid] += red[tid + s2];
        __syncthreads();
    }
    float r = rsqrtf(red[0] * (1.0f / DD) + 1e-5f);
    __hip_bfloat16* o = out + (size_t)row * DD;
    o[tid]       = __float2bfloat16(d0 * r * g[tid]       + b[tid]);
    o[tid + 256] = __float2bfloat16(d1 * r * g[tid + 256] + b[tid + 256]);
    o[tid + 512] = __float2bfloat16(d2 * r * g[tid + 512] + b[tid + 512]);
}

// ---------------- W [K,N] f32  ->  Wt [N,K] bf16 ----------------
__global__ __launch_bounds__(256) void transpose_cvt_kernel(
    const float* __restrict__ W, __hip_bfloat16* __restrict__ Wt, int K, int N) {
    __shared__ float t[32][33];
    int bn = blockIdx.x * 32, bk = blockIdx.y * 32;
    int tx = threadIdx.x & 31, ty = threadIdx.x >> 5;
    for (int r = ty; r < 32; r += 8)
        t[r][tx] = (bn + tx < N) ? W[(size_t)(bk + r) * N + bn + tx] : 0.0f;
    __syncthreads();
    for (int r = ty; r < 32; r += 8) {
        int n = bn + r;
        if (n < N) Wt[(size_t)n * K + bk + tx] = __float2bfloat16(t[tx][r]);
    }
}

// LDS rows are 64B (32 bf16); 16B slots XOR-swizzled by ((row>>1)&3).
#define LDSOFF(row, ks) (((row) * 64) + ((((ks) ^ (((row) >> 1) & 3))) << 4))
// swizzled byte offset within a [rows][128B] LDS tile
#define SWZ128(row, byteoff) \
    ((row) * 128 + (((((byteoff) >> 4) ^ ((row) & 7)) & 7) << 4) + ((byteoff) & 15))

// ---------------- generic bf16 MFMA GEMM ----------------
template<int BM, int BN>
__global__ __launch_bounds__(256) void gemm_mfma_kernel(
    const __hip_bfloat16* __restrict__ A, const __hip_bfloat16* __restrict__ Wt,
    const float* __restrict__ bias, const float* __restrict__ residual,
    float* __restrict__ Cf, __hip_bfloat16* __restrict__ Cb,
    int M, int N, int K, int do_gelu) {
    constexpr int BK = 32;
    constexpr int UA = (BM * 4) / 256;
    constexpr int UB = (BN * 4) / 256;
    constexpr int FM = BM / 32;
    constexpr int FN = BN / 32;
    __shared__ __align__(16) char As[BM * 64];
    __shared__ __align__(16) char Bs[BN * 64];

    const int tid = threadIdx.x;
    const int lane = tid & 63;
    const int wid = tid >> 6;
    const int bm = blockIdx.y * BM;
    const int bn = blockIdx.x * BN;
    const int r16 = lane & 15;
    const int kg = lane >> 4;
    const int wm = (wid >> 1) * (FM * 16);
    const int wn = (wid & 1) * (FN * 16);

    f32x4 acc[FM][FN];
    const f32x4 zf = {0.0f, 0.0f, 0.0f, 0.0f};
#pragma unroll
    for (int i = 0; i < FM; ++i)
#pragma unroll
        for (int j = 0; j < FN; ++j) acc[i][j] = zf;

    int4v areg[UA], breg[UB];
    const int4v zi = {0, 0, 0, 0};

#pragma unroll
    for (int u = 0; u < UA; ++u) {
        int c = tid + u * 256, row = c >> 2, sl = c & 3;
        areg[u] = *(const int4v*)(A + (size_t)(bm + row) * K + sl * 8);
    }
#pragma unroll
    for (int u = 0; u < UB; ++u) {
        int c = tid + u * 256, row = c >> 2, sl = c & 3;
        int4v bv = zi;
        if (bn + row < N) bv = *(const int4v*)(Wt + (size_t)(bn + row) * K + sl * 8);
        breg[u] = bv;
    }

    for (int k0 = 0; k0 < K; k0 += BK) {
        __syncthreads();
#pragma unroll
        for (int u = 0; u < UA; ++u) {
            int c = tid + u * 256, row = c >> 2, sl = c & 3;
            *(int4v*)(As + LDSOFF(row, sl)) = areg[u];
        }
#pragma unroll
        for (int u = 0; u < UB; ++u) {
            int c = tid + u * 256, row = c >> 2, sl = c & 3;
            *(int4v*)(Bs + LDSOFF(row, sl)) = breg[u];
        }
        __syncthreads();
        int kn = k0 + BK;
        if (kn < K) {
#pragma unroll
            for (int u = 0; u < UA; ++u) {
                int c = tid + u * 256, row = c >> 2, sl = c & 3;
                areg[u] = *(const int4v*)(A + (size_t)(bm + row) * K + kn + sl * 8);
            }
#pragma unroll
            for (int u = 0; u < UB; ++u) {
                int c = tid + u * 256, row = c >> 2, sl = c & 3;
                int4v bv = zi;
                if (bn + row < N) bv = *(const int4v*)(Wt + (size_t)(bn + row) * K + kn + sl * 8);
                breg[u] = bv;
            }
        }
        short8v af[FM], bfr[FN];
#pragma unroll
        for (int i = 0; i < FM; ++i) {
            int row = wm + i * 16 + r16;
            af[i] = *(const short8v*)(As + LDSOFF(row, kg));
        }
#pragma unroll
        for (int j = 0; j < FN; ++j) {
            int row = wn + j * 16 + r16;
            bfr[j] = *(const short8v*)(Bs + LDSOFF(row, kg));
        }
#pragma unroll
        for (int i = 0; i < FM; ++i)
#pragma unroll
            for (int j = 0; j < FN; ++j)
                acc[i][j] = __builtin_amdgcn_mfma_f32_16x16x32_bf16(
                    af[i], bfr[j], acc[i][j], 0, 0, 0);
    }

    const int rg = lane >> 4;
#pragma unroll
    for (int i = 0; i < FM; ++i) {
#pragma unroll
        for (int j = 0; j < FN; ++j) {
            int col = bn + wn + j * 16 + r16;
            if (col < N) {
#pragma unroll
                for (int r = 0; r < 4; ++r) {
                    int row = bm + wm + i * 16 + rg * 4 + r;
                    float v = acc[i][j][r];
                    if (bias) v += bias[col];
                    if (do_gelu) v = gelu_f(v);
                    size_t o = (size_t)row * N + col;
                    if (residual) v += residual[o];
                    if (Cf) Cf[o] = v;
                    else Cb[o] = __float2bfloat16(v);
                }
            }
        }
    }
}

// ---------------- QKV GEMM: xn @ [wq|wk|wv]^T -> Q(scaled), K, V^T ----------------
// Q,K: [B*H, S, DK] bf16. Vt: [B*H, DK, S] bf16. BM=BN=128, N=2304 exact.
__global__ __launch_bounds__(256) void qkv_gemm_kernel(
    const __hip_bfloat16* __restrict__ A, const __hip_bfloat16* __restrict__ Wt,
    __hip_bfloat16* __restrict__ qh, __hip_bfloat16* __restrict__ kh,
    __hip_bfloat16* __restrict__ vt) {
    constexpr int BM = 128, BN = 128, BK = 32;
    constexpr int K = DD;
    constexpr int UA = 2, UB = 2, FM = 4, FN = 4;
    __shared__ __align__(16) char As[BM * 64];
    __shared__ __align__(16) char Bs[BN * 64];

    const int tid = threadIdx.x;
    const int lane = tid & 63;
    const int wid = tid >> 6;
    const int bm = blockIdx.y * BM;
    const int bn = blockIdx.x * BN;
    const int r16 = lane & 15;
    const int kg = lane >> 4;
    const int wm = (wid >> 1) * 64;
    const int wn = (wid & 1) * 64;

    f32x4 acc[FM][FN];
    const f32x4 zf = {0.0f, 0.0f, 0.0f, 0.0f};
#pragma unroll
    for (int i = 0; i < FM; ++i)
#pragma unroll
        for (int j = 0; j < FN; ++j) acc[i][j] = zf;

    int4v areg[UA], breg[UB];
#pragma unroll
    for (int u = 0; u < UA; ++u) {
        int c = tid + u * 256, row = c >> 2, sl = c & 3;
        areg[u] = *(const int4v*)(A + (size_t)(bm + row) * K + sl * 8);
    }
#pragma unroll
    for (int u = 0; u < UB; ++u) {
        int c = tid + u * 256, row = c >> 2, sl = c & 3;
        breg[u] = *(const int4v*)(Wt + (size_t)(bn + row) * K + sl * 8);
    }

    for (int k0 = 0; k0 < K; k0 += BK) {
        __syncthreads();
#pragma unroll
        for (int u = 0; u < UA; ++u) {
            int c = tid + u * 256, row = c >> 2, sl = c & 3;
            *(int4v*)(As + LDSOFF(row, sl)) = areg[u];
        }
#pragma unroll
        for (int u = 0; u < UB; ++u) {
            int c = tid + u * 256, row = c >> 2, sl = c & 3;
            *(int4v*)(Bs + LDSOFF(row, sl)) = breg[u];
        }
        __syncthreads();
        int kn = k0 + BK;
        if (kn < K) {
#pragma unroll
            for (int u = 0; u < UA; ++u) {
                int c = tid + u * 256, row = c >> 2, sl = c & 3;
                areg[u] = *(const int4v*)(A + (size_t)(bm + row) * K + kn + sl * 8);
            }
#pragma unroll
            for (int u = 0; u < UB; ++u) {
                int c = tid + u * 256, row = c >> 2, sl = c & 3;
                breg[u] = *(const int4v*)(Wt + (size_t)(bn + row) * K + kn + sl * 8);
            }
        }
        short8v af[FM], bfr[FN];
#pragma unroll
        for (int i = 0; i < FM; ++i)
            af[i] = *(const short8v*)(As + LDSOFF(wm + i * 16 + r16, kg));
#pragma unroll
        for (int j = 0; j < FN; ++j)
            bfr[j] = *(const short8v*)(Bs + LDSOFF(wn + j * 16 + r16, kg));
#pragma unroll
        for (int i = 0; i < FM; ++i)
#pragma unroll
            for (int j = 0; j < FN; ++j)
                acc[i][j] = __builtin_amdgcn_mfma_f32_16x16x32_bf16(
                    af[i], bfr[j], acc[i][j], 0, 0, 0);
    }

#pragma unroll
    for (int i = 0; i < FM; ++i) {
#pragma unroll
        for (int j = 0; j < FN; ++j) {
            int col = bn + wn + j * 16 + r16;
#pragma unroll
            for (int r = 0; r < 4; ++r) {
                int row = bm + wm + i * 16 + kg * 4 + r;   // b*S + s
                int b = row >> 10, s = row & (SS - 1);
                float v = acc[i][j][r];
                if (col < DD) {
                    int h = col >> 6, d = col & 63;
                    qh[((size_t)(b * HH + h) * SS + s) * DKK + d] =
                        __float2bfloat16(v * 0.125f);       // fold 1/sqrt(64)
                } else if (col < 2 * DD) {
                    int c = col - DD, h = c >> 6, d = c & 63;
                    kh[((size_t)(b * HH + h) * SS + s) * DKK + d] = __float2bfloat16(v);
                } else {
                    int c = col - 2 * DD, h = c >> 6, d = c & 63;
                    vt[((size_t)(b * HH + h) * DKK + d) * SS + s] = __float2bfloat16(v);
                }
            }
        }
    }
}

// ---------------- flash attention: block = (b*h, q-tile of 64) ----------------
// 4 waves x 16 q-rows. K tile [64k,64d] and Vt tile [64d,64k] in swizzled LDS.
__global__ __launch_bounds__(256) void flash_attn_kernel(
    const __hip_bfloat16* __restrict__ qh, const __hip_bfloat16* __restrict__ kh,
    const __hip_bfloat16* __restrict__ vt, __hip_bfloat16* __restrict__ ctx) {
    __shared__ __align__(16) char Ks[KVBLK * 128];
    __shared__ __align__(16) char Vs[DKK * 128];
    __shared__ __align__(16) char Ps[4][16 * 128];

    const int bh = blockIdx.x;                       // 0..23
    const int qt = (gridDim.y - 1) - blockIdx.y;     // heavy tiles first
    const int q0 = qt * QBLK;
    const int b = bh / HH;
    const int h = bh - b * HH;
    const int tid = threadIdx.x;
    const int lane = tid & 63;
    const int w = tid >> 6;
    const int r16 = lane & 15;
    const int kg = lane >> 4;
    char* Pw = Ps[w];

    // Q fragments (A-operand), scaled already
    const size_t qbase = ((size_t)bh * SS + q0 + w * 16 + r16) * DKK;
    short8v qf0 = *(const short8v*)(qh + qbase + kg * 8);
    short8v qf1 = *(const short8v*)(qh + qbase + 32 + kg * 8);

    f32x4 acc_o[4];
    const f32x4 zf = {0.0f, 0.0f, 0.0f, 0.0f};
    float m[4], l[4];
#pragma unroll
    for (int j = 0; j < 4; ++j) acc_o[j] = zf;
#pragma unroll
    for (int r = 0; r < 4; ++r) { m[r] = -1e30f; l[r] = 0.0f; }

    const int nt = qt + 1;
    for (int t = 0; t < nt; ++t) {
        __syncthreads();
        {
            const __hip_bfloat16* kp = kh + ((size_t)bh * SS + t * KVBLK) * DKK;
            const __hip_bfloat16* vp = vt + (size_t)bh * DKK * SS + t * KVBLK;
#pragma unroll
            for (int u = 0; u < 2; ++u) {
                int c = tid + u * 256;              // 0..511
                int row = c >> 3, slot = c & 7;
                *(int4v*)(Ks + SWZ128(row, slot * 16)) =
                    *(const int4v*)(kp + (size_t)row * DKK + slot * 8);
                *(int4v*)(Vs + SWZ128(row, slot * 16)) =
                    *(const int4v*)(vp + (size_t)row * SS + slot * 8);
            }
        }
        __syncthreads();

        // S = Q @ K^T  [16 q x 64 k] per wave
        f32x4 s[4];
#pragma unroll
        for (int j = 0; j < 4; ++j) s[j] = zf;
#pragma unroll
        for (int j = 0; j < 4; ++j) {
            short8v k0f = *(const short8v*)(Ks + SWZ128(j * 16 + r16, kg * 16));
            short8v k1f = *(const short8v*)(Ks + SWZ128(j * 16 + r16, 64 + kg * 16));
            s[j] = __builtin_amdgcn_mfma_f32_16x16x32_bf16(qf0, k0f, s[j], 0, 0, 0);
            s[j] = __builtin_amdgcn_mfma_f32_16x16x32_bf16(qf1, k1f, s[j], 0, 0, 0);
        }

        if (t == qt) {   // causal mask on diagonal tile
#pragma unroll
            for (int j = 0; j < 4; ++j)
#pragma unroll
                for (int r = 0; r < 4; ++r)
                    if (j * 16 + r16 > w * 16 + kg * 4 + r) s[j][r] = -1e30f;
        }

        // online softmax: per-row (4 rows/lane) max & sum over 64 cols
        float alpha[4], rsum[4];
#pragma unroll
        for (int r = 0; r < 4; ++r) {
            float v = fmaxf(fmaxf(s[0][r], s[1][r]), fmaxf(s[2][r], s[3][r]));
#pragma unroll
            for (int d2 = 1; d2 < 16; d2 <<= 1)
                v = fmaxf(v, __shfl_xor(v, d2));
            float mnew = fmaxf(m[r], v);
            alpha[r] = __expf(m[r] - mnew);
            m[r] = mnew;
            rsum[r] = 0.0f;
        }
#pragma unroll
        for (int j = 0; j < 4; ++j)
#pragma unroll
            for (int r = 0; r < 4; ++r) {
                float p = __expf(s[j][r] - m[r]);
                rsum[r] += p;
                *(__hip_bfloat16*)(Pw + SWZ128(kg * 4 + r, (j * 16 + r16) * 2)) =
                    __float2bfloat16(p);
            }
#pragma unroll
        for (int r = 0; r < 4; ++r) {
#pragma unroll
            for (int d2 = 1; d2 < 16; d2 <<= 1)
                rsum[r] += __shfl_xor(rsum[r], d2);
            l[r] = l[r] * alpha[r] + rsum[r];
        }
#pragma unroll
        for (int j = 0; j < 4; ++j)
#pragma unroll
            for (int r = 0; r < 4; ++r) acc_o[j][r] *= alpha[r];

        // PV: O += P @ V   (wave-local LDS round-trip for P re-fragmenting)
        short8v pa0 = *(const short8v*)(Pw + SWZ128(r16, kg * 16));
        short8v pa1 = *(const short8v*)(Pw + SWZ128(r16, 64 + kg * 16));
#pragma unroll
        for (int j = 0; j < 4; ++j) {
            short8v v0f = *(const short8v*)(Vs + SWZ128(j * 16 + r16, kg * 16));
            short8v v1f = *(const short8v*)(Vs + SWZ128(j * 16 + r16, 64 + kg * 16));
            acc_o[j] = __builtin_amdgcn_mfma_f32_16x16x32_bf16(pa0, v0f, acc_o[j], 0, 0, 0);
            acc_o[j] = __builtin_amdgcn_mfma_f32_16x16x32_bf16(pa1, v1f, acc_o[j], 0, 0, 0);
        }
    }

    // normalize + store ctx [B*S, D] bf16
#pragma unroll
    for (int r = 0; r < 4; ++r) {
        float inv = 1.0f / l[r];
        int row = q0 + w * 16 + kg * 4 + r;
        __hip_bfloat16* cp = ctx + ((size_t)(b * SS) + row) * DD + h * DKK;
#pragma unroll
        for (int j = 0; j < 4; ++j)
            cp[j * 16 + r16] = __float2bfloat16(acc_o[j][r] * inv);
    }
}

// ---------------- fp32 fallback GEMM / attention (round-1, proven) ----------------
__global__ __launch_bounds__(256) void gemm_kernel(
    const float* __restrict__ A, const float* __restrict__ W,
    const float* __restrict__ bias, const float* __restrict__ residual,
    float* __restrict__ C, int M, int N, int K, int do_gelu) {
    __shared__ float As[16][64];
    __shared__ float Ws[16][68];
    int tid = threadIdx.x;
    int bn = blockIdx.x * 64, bm = blockIdx.y * 64;
    int tx = tid & 15, ty = tid >> 4;
    int ar = tid >> 2, ak = (tid & 3) << 2;
    int wr = tid >> 4, wc = (tid & 15) << 2;
    bool n_vec = ((N & 3) == 0);
    float acc[4][4] = {};
    for (int k0 = 0; k0 < K; k0 += 16) {
        float4 av = *(const float4*)&A[(size_t)(bm + ar) * K + (k0 + ak)];
        As[ak + 0][ar] = av.x; As[ak + 1][ar] = av.y;
        As[ak + 2][ar] = av.z; As[ak + 3][ar] = av.w;
        int gn = bn + wc;
        const float* wp = &W[(size_t)(k0 + wr) * N + gn];
        float w0, w1, w2, w3;
        if (n_vec && gn + 3 < N) {
            float4 wv4 = *(const float4*)wp;
            w0 = wv4.x; w1 = wv4.y; w2 = wv4.z; w3 = wv4.w;
        } else {
            w0 = (gn + 0 < N) ? wp[0] : 0.0f;
            w1 = (gn + 1 < N) ? wp[1] : 0.0f;
            w2 = (gn + 2 < N) ? wp[2] : 0.0f;
            w3 = (gn + 3 < N) ? wp[3] : 0.0f;
        }
        Ws[wr][wc + 0] = w0; Ws[wr][wc + 1] = w1;
        Ws[wr][wc + 2] = w2; Ws[wr][wc + 3] = w3;
        __syncthreads();
#pragma unroll
        for (int kk = 0; kk < 16; ++kk) {
            float a[4], w[4];
#pragma unroll
            for (int i = 0; i < 4; ++i) a[i] = As[kk][ty * 4 + i];
#pragma unroll
            for (int j = 0; j < 4; ++j) w[j] = Ws[kk][tx * 4 + j];
#pragma unroll
            for (int i = 0; i < 4; ++i)
#pragma unroll
                for (int j = 0; j < 4; ++j)
                    acc[i][j] = fmaf(a[i], w[j], acc[i][j]);
        }
        __syncthreads();
    }
#pragma unroll
    for (int i = 0; i < 4; ++i) {
        int row = bm + ty * 4 + i;
#pragma unroll
        for (int j = 0; j < 4; ++j) {
            int col = bn + tx * 4 + j;
            if (col < N) {
                float val = acc[i][j];
                if (bias) val += bias[col];
                if (do_gelu) val = gelu_f(val);
                if (residual) val += residual[(size_t)row * N + col];
                C[(size_t)row * N + col] = val;
            }
        }
    }
}

__global__ __launch_bounds__(256) void attn_kernel(
    const float* __restrict__ q, const float* __restrict__ k,
    const float* __restrict__ v, float* __restrict__ ctx) {
    int bid = blockIdx.x;
    int qi = bid & (SS - 1);
    int bh = bid >> 10;
    int h = bh % HH;
    int b = bh / HH;
    int tid = threadIdx.x;
    __shared__ float qs[DKK];
    __shared__ float p[SS];
    __shared__ float red[256];
    __shared__ float ctx_red[4][DKK];
    const float* qrow = q + ((size_t)(b * SS + qi)) * DD + h * DKK;
    if (tid < DKK) qs[tid] = qrow[tid];
    __syncthreads();
    int nk = qi + 1;
    const float scale = 0.125f;
    for (int ki = tid; ki < nk; ki += 256) {
        const float* krow = k + ((size_t)(b * SS + ki)) * DD + h * DKK;
        float dot = 0.0f;
#pragma unroll
        for (int d = 0; d < DKK; d += 4) {
            float4 kv = *(const float4*)&krow[d];
            dot += qs[d] * kv.x + qs[d + 1] * kv.y + qs[d + 2] * kv.z + qs[d + 3] * kv.w;
        }
        p[ki] = dot * scale;
    }
    __syncthreads();
    float lmax = -1e30f;
    for (int ki = tid; ki < nk; ki += 256) lmax = fmaxf(lmax, p[ki]);
    red[tid] = lmax;
    __syncthreads();
    for (int s2 = 128; s2 > 0; s2 >>= 1) {
        if (tid < s2) red[tid] = fmaxf(red[tid], red[tid + s2]);
        __syncthreads();
    }
    float mm = red[0];
    __syncthreads();
    float lsum = 0.0f;
    for (int ki = tid; ki < nk; ki += 256) {
        float e = __expf(p[ki] - mm);
        p[ki] = e;
        lsum += e;
    }
    red[tid] = lsum;
    __syncthreads();
    for (int s2 = 128; s2 > 0; s2 >>= 1) {
        if (tid < s2) red[tid] += red[tid + s2];
        __syncthreads();
    }
    float inv = 1.0f / red[0];
    int d = tid & 63;
    int chunk = tid >> 6;
    float accd = 0.0f;
    for (int ki = chunk; ki < nk; ki += 4)
        accd += p[ki] * v[((size_t)(b * SS + ki)) * DD + h * DKK + d];
    ctx_red[chunk][d] = accd;
    __syncthreads();
    if (tid < DKK) {
        float sum = (ctx_red[0][tid] + ctx_red[1][tid]) + (ctx_red[2][tid] + ctx_red[3][tid]);
        ctx[((size_t)(b * SS + qi)) * DD + h * DKK + tid] = sum * inv;
    }
}

// ---------------- host-side orchestration ----------------
extern "C" void kernel_launch(void* const* d_in, const int* in_sizes, int n_in,
                              void* d_out, int out_size, void* d_ws, size_t ws_size,
                              hipStream_t stream) {
    const int*   ids    = (const int*)  d_in[0];
    const float* tok    = (const float*)d_in[1];
    const float* pos    = (const float*)d_in[2];
    const float* wq     = (const float*)d_in[3];
    const float* wk     = (const float*)d_in[4];
    const float* wv     = (const float*)d_in[5];
    const float* wo     = (const float*)d_in[6];
    const float* bo     = (const float*)d_in[7];
    const float* fc_w   = (const float*)d_in[8];
    const float* fc_b   = (const float*)d_in[9];
    const float* proj_w = (const float*)d_in[10];
    const float* proj_b = (const float*)d_in[11];
    const float* ln1_g  = (const float*)d_in[12];
    const float* ln1_b  = (const float*)d_in[13];
    const float* ln2_g  = (const float*)d_in[14];
    const float* ln2_b  = (const float*)d_in[15];
    const float* lnf_g  = (const float*)d_in[16];
    const float* lnf_b  = (const float*)d_in[17];
    const float* out_w  = (const float*)d_in[18];
    float* out = (float*)d_out;

    dim3 blk(256);

    const size_t SZ_X   = (size_t)NROWS * DD * 4;
    const size_t SZ_XN  = (size_t)NROWS * DD * 2;
    const size_t SZ_HD  = (size_t)BB * HH * SS * DKK * 2;   // one of qh/kh/vt
    const size_t SZ_CTX = (size_t)NROWS * DD * 2;
    const size_t SZ_H   = (size_t)NROWS * FF * 2;
    const size_t SZ_WT  = (size_t)50304 * DD * 2;
    const size_t NEED   = SZ_X + SZ_XN + 3 * SZ_HD + SZ_CTX + SZ_H + SZ_WT;

    if (ws_size >= NEED) {
        char* p = (char*)d_ws;
        float*          x    = (float*)p;          p += SZ_X;
        __hip_bfloat16* xn   = (__hip_bfloat16*)p; p += SZ_XN;
        __hip_bfloat16* qhb  = (__hip_bfloat16*)p; p += SZ_HD;
        __hip_bfloat16* khb  = (__hip_bfloat16*)p; p += SZ_HD;
        __hip_bfloat16* vtb  = (__hip_bfloat16*)p; p += SZ_HD;
        __hip_bfloat16* ctx  = (__hip_bfloat16*)p; p += SZ_CTX;
        __hip_bfloat16* hbuf = (__hip_bfloat16*)p; p += SZ_H;
        __hip_bfloat16* Wt   = (__hip_bfloat16*)p;

        dim3 tD(DD / 32, DD / 32);
        dim3 tF(FF / 32, DD / 32);
        dim3 tP(DD / 32, FF / 32);
        dim3 tV((VV + 31) / 32, DD / 32);

        dim3 gQKV(QKVN / 128, NROWS / 128);        // 18 x 16
        dim3 gFC(FF / 128, NROWS / 128);           // 24 x 16
        dim3 gWO(DD / 64, NROWS / 64);             // 12 x 32
        dim3 gV((VV + 127) / 128, NROWS / 128);    // 393 x 16
        dim3 gA(BB * HH, SS / QBLK);               // 24 x 16

        embed_kernel<<<NROWS, blk, 0, stream>>>(ids, tok, pos, x);

        for (int l = 0; l < LL; ++l) {
            const float* wq_l = wq + (size_t)l * DD * DD;
            const float* wk_l = wk + (size_t)l * DD * DD;
            const float* wv_l = wv + (size_t)l * DD * DD;
            const float* wo_l = wo + (size_t)l * DD * DD;
            const float* fc_w_l = fc_w + (size_t)l * DD * FF;
            const float* pj_w_l = proj_w + (size_t)l * FF * DD;

            ln_bf16_kernel<<<NROWS, blk, 0, stream>>>(x, ln1_g + l * DD, ln1_b + l * DD, xn);
            transpose_cvt_kernel<<<tD, blk, 0, stream>>>(wq_l, Wt, DD, DD);
            transpose_cvt_kernel<<<tD, blk, 0, stream>>>(wk_l, Wt + (size_t)DD * DD, DD, DD);
            transpose_cvt_kernel<<<tD, blk, 0, stream>>>(wv_l, Wt + (size_t)2 * DD * DD, DD, DD);
            qkv_gemm_kernel<<<gQKV, blk, 0, stream>>>(xn, Wt, qhb, khb, vtb);
            flash_attn_kernel<<<gA, blk, 0, stream>>>(qhb, khb, vtb, ctx);
            transpose_cvt_kernel<<<tD, blk, 0, stream>>>(wo_l, Wt, DD, DD);
            gemm_mfma_kernel<64, 64><<<gWO, blk, 0, stream>>>(
                ctx, Wt, bo + l * DD, x, x, nullptr, NROWS, DD, DD, 0);
            ln_bf16_kernel<<<NROWS, blk, 0, stream>>>(x, ln2_g + l * DD, ln2_b + l * DD, xn);
            transpose_cvt_kernel<<<tF, blk, 0, stream>>>(fc_w_l, Wt, DD, FF);
            gemm_mfma_kernel<128, 128><<<gFC, blk, 0, stream>>>(
                xn, Wt, fc_b + l * FF, nullptr, nullptr, hbuf, NROWS, FF, DD, 1);
            transpose_cvt_kernel<<<tP, blk, 0, stream>>>(pj_w_l, Wt, FF, DD);
            gemm_mfma_kernel<64, 64><<<gWO, blk, 0, stream>>>(
                hbuf, Wt, proj_b + l * DD, x, x, nullptr, NROWS, DD, FF, 0);
        }

        ln_bf16_kernel<<<NROWS, blk, 0, stream>>>(x, lnf_g, lnf_b, xn);
        transpose_cvt_kernel<<<tV, blk, 0, stream>>>(out_w, Wt, DD, VV);
        gemm_mfma_kernel<128, 128><<<gV, blk, 0, stream>>>(
            xn, Wt, nullptr, nullptr, out, nullptr, NROWS, VV, DD, 0);
        return;
    }

    // ---- fallback: proven fp32 path ----
    const size_t XSZ = (size_t)NROWS * DD;
    float* ws = (float*)d_ws;
    float* x  = ws;
    float* xn = x  + XSZ;
    float* qb = xn + XSZ;
    float* kb = qb + XSZ;
    float* vb = kb + XSZ;
    float* cb = vb + XSZ;
    float* hb = cb + XSZ;

    dim3 gD((DD + 63) / 64, NROWS / 64);
    dim3 gF((FF + 63) / 64, NROWS / 64);
    dim3 gV2((VV + 63) / 64, NROWS / 64);

    embed_kernel<<<NROWS, blk, 0, stream>>>(ids, tok, pos, x);
    for (int l = 0; l < LL; ++l) {
        const float* wq_l = wq + (size_t)l * DD * DD;
        const float* wk_l = wk + (size_t)l * DD * DD;
        const float* wv_l = wv + (size_t)l * DD * DD;
        const float* wo_l = wo + (size_t)l * DD * DD;
        const float* fc_w_l = fc_w + (size_t)l * DD * FF;
        const float* pj_w_l = proj_w + (size_t)l * FF * DD;
        ln_kernel<<<NROWS, blk, 0, stream>>>(x, ln1_g + l * DD, ln1_b + l * DD, xn);
        gemm_kernel<<<gD, blk, 0, stream>>>(xn, wq_l, nullptr, nullptr, qb, NROWS, DD, DD, 0);
        gemm_kernel<<<gD, blk, 0, stream>>>(xn, wk_l, nullptr, nullptr, kb, NROWS, DD, DD, 0);
        gemm_kernel<<<gD, blk, 0, stream>>>(xn, wv_l, nullptr, nullptr, vb, NROWS, DD, DD, 0);
        attn_kernel<<<BB * HH * SS, blk, 0, stream>>>(qb, kb, vb, cb);
        gemm_kernel<<<gD, blk, 0, stream>>>(cb, wo_l, bo + l * DD, x, x, NROWS, DD, DD, 0);
        ln_kernel<<<NROWS, blk, 0, stream>>>(x, ln2_g + l * DD, ln2_b + l * DD, xn);
        gemm_kernel<<<gF, blk, 0, stream>>>(xn, fc_w_l, fc_b + l * FF, nullptr, hb, NROWS, FF, DD, 1);
        gemm_kernel<<<gD, blk, 0, stream>>>(hb, pj_w_l, proj_b + l * DD, x, x, NROWS, DD, FF, 0);
    }
    ln_kernel<<<NROWS, blk, 0, stream>>>(x, lnf_g, lnf_b, xn);
    gemm_kernel<<<gV2, blk, 0, stream>>>(xn, out_w, nullptr, nullptr, out, NROWS, VV, DD, 0);
}

// Round 4
// 1545.896 us; speedup vs baseline: 6.8173x; 1.0175x over previous
//
#include <hip/hip_runtime.h>
#include <hip/hip_bf16.h>
#include <math.h>

// GPT-2 small forward: B=2, S=1024, V=50257, D=768, H=12, L=6, F=3072, DK=64
#define BB 2
#define SS 1024
#define DD 768
#define HH 12
#define LL 6
#define FF 3072
#define VV 50257
#define DKK 64
#define NROWS (BB * SS)   // 2048
#define QKVN (3 * DD)     // 2304
#define QBLK 64
#define KVBLK 64

// Wt_all element layout per layer: [qkv 2304x768 | wo 768x768 | fc 3072x768 | proj 768x3072]
#define OFF_QKV 0
#define OFF_WO  1769472
#define OFF_FC  2359296
#define OFF_PROJ 4718592
#define PL      7077888   // elements per layer

typedef __attribute__((ext_vector_type(8))) short short8v;  // 8 bf16 = 4 VGPRs
typedef __attribute__((ext_vector_type(4))) float f32x4;
typedef __attribute__((ext_vector_type(4))) int int4v;

__device__ __forceinline__ float gelu_f(float x) {
    return 0.5f * x * (1.0f + erff(x * 0.70710678118654752440f));
}

// ---------------- embedding ----------------
__global__ __launch_bounds__(256) void embed_kernel(
    const int* __restrict__ ids, const float* __restrict__ tok,
    const float* __restrict__ pos, float* __restrict__ x) {
    int row = blockIdx.x;
    int s = row & (SS - 1);
    int id = ids[row];
    const float* t = tok + (size_t)id * DD;
    const float* p = pos + (size_t)s * DD;
    float* xr = x + (size_t)row * DD;
    for (int i = threadIdx.x; i < DD; i += 256)
        xr[i] = t[i] + p[i];
}

// ---------------- layernorm (fp32 in, fp32 out) — fallback ----------------
__global__ __launch_bounds__(256) void ln_kernel(
    const float* __restrict__ x, const float* __restrict__ g,
    const float* __restrict__ b, float* __restrict__ out) {
    int row = blockIdx.x;
    int tid = threadIdx.x;
    const float* xr = x + (size_t)row * DD;
    float v0 = xr[tid], v1 = xr[tid + 256], v2 = xr[tid + 512];
    __shared__ float red[256];
    red[tid] = v0 + v1 + v2;
    __syncthreads();
    for (int s2 = 128; s2 > 0; s2 >>= 1) {
        if (tid < s2) red[tid] += red[tid + s2];
        __syncthreads();
    }
    float mu = red[0] * (1.0f / DD);
    __syncthreads();
    float d0 = v0 - mu, d1 = v1 - mu, d2 = v2 - mu;
    red[tid] = d0 * d0 + d1 * d1 + d2 * d2;
    __syncthreads();
    for (int s2 = 128; s2 > 0; s2 >>= 1) {
        if (tid < s2) red[tid] += red[tid + s2];
        __syncthreads();
    }
    float r = rsqrtf(red[0] * (1.0f / DD) + 1e-5f);
    float* o = out + (size_t)row * DD;
    o[tid]       = d0 * r * g[tid]       + b[tid];
    o[tid + 256] = d1 * r * g[tid + 256] + b[tid + 256];
    o[tid + 512] = d2 * r * g[tid + 512] + b[tid + 512];
}

// ---------------- layernorm (fp32 in, bf16 out) ----------------
__global__ __launch_bounds__(256) void ln_bf16_kernel(
    const float* __restrict__ x, const float* __restrict__ g,
    const float* __restrict__ b, __hip_bfloat16* __restrict__ out) {
    int row = blockIdx.x;
    int tid = threadIdx.x;
    const float* xr = x + (size_t)row * DD;
    float v0 = xr[tid], v1 = xr[tid + 256], v2 = xr[tid + 512];
    __shared__ float red[256];
    red[tid] = v0 + v1 + v2;
    __syncthreads();
    for (int s2 = 128; s2 > 0; s2 >>= 1) {
        if (tid < s2) red[tid] += red[tid + s2];
        __syncthreads();
    }
    float mu = red[0] * (1.0f / DD);
    __syncthreads();
    float d0 = v0 - mu, d1 = v1 - mu, d2 = v2 - mu;
    red[tid] = d0 * d0 + d1 * d1 + d2 * d2;
    __syncthreads();
    for (int s2 = 128; s2 > 0; s2 >>= 1) {
        if (tid < s2) red[tid] += red[tid + s2];
        __syncthreads();
    }
    float r = rsqrtf(red[0] * (1.0f / DD) + 1e-5f);
    __hip_bfloat16* o = out + (size_t)row * DD;
    o[tid]       = __float2bfloat16(d0 * r * g[tid]       + b[tid]);
    o[tid + 256] = __float2bfloat16(d1 * r * g[tid + 256] + b[tid + 256]);
    o[tid + 512] = __float2bfloat16(d2 * r * g[tid + 512] + b[tid + 512]);
}

// ---------------- single W [K,N] f32 -> Wt [N,K] bf16 (mid path) ----------------
__global__ __launch_bounds__(256) void transpose_cvt_kernel(
    const float* __restrict__ W, __hip_bfloat16* __restrict__ Wt, int K, int N) {
    __shared__ float t[32][33];
    int bn = blockIdx.x * 32, bk = blockIdx.y * 32;
    int tx = threadIdx.x & 31, ty = threadIdx.x >> 5;
    for (int r = ty; r < 32; r += 8)
        t[r][tx] = (bn + tx < N) ? W[(size_t)(bk + r) * N + bn + tx] : 0.0f;
    __syncthreads();
    for (int r = ty; r < 32; r += 8) {
        int n = bn + r;
        if (n < N) Wt[(size_t)n * K + bk + tx] = __float2bfloat16(t[tx][r]);
    }
}

// ---------------- ALL weight transposes in one launch (big-ws path) ----------------
// grid: 6 layers x 6912 tiles + 37704 out_w tiles = 79176 blocks.
__global__ __launch_bounds__(256) void transpose_all_kernel(
    const float* __restrict__ wq, const float* __restrict__ wk,
    const float* __restrict__ wv, const float* __restrict__ wo,
    const float* __restrict__ fc_w, const float* __restrict__ proj_w,
    const float* __restrict__ out_w, __hip_bfloat16* __restrict__ Wt_all) {
    int bid = blockIdx.x;
    const float* W;
    __hip_bfloat16* Wt;
    int K, N, tn, tk;
    if (bid < 6 * 6912) {
        int l = bid / 6912, r = bid % 6912;
        __hip_bfloat16* base = Wt_all + (size_t)l * PL;
        if (r < 1728) {                      // wq/wk/wv -> qkv Wt rows
            int which = r / 576, idx = r % 576;
            W = (which == 0 ? wq : (which == 1 ? wk : wv)) + (size_t)l * DD * DD;
            Wt = base + (size_t)which * DD * DD;
            K = DD; N = DD; tn = idx % 24; tk = idx / 24;
        } else if (r < 2304) {               // wo
            int idx = r - 1728;
            W = wo + (size_t)l * DD * DD;
            Wt = base + OFF_WO;
            K = DD; N = DD; tn = idx % 24; tk = idx / 24;
        } else if (r < 4608) {               // fc  [768,3072]
            int idx = r - 2304;
            W = fc_w + (size_t)l * DD * FF;
            Wt = base + OFF_FC;
            K = DD; N = FF; tn = idx % 96; tk = idx / 96;
        } else {                             // proj [3072,768]
            int idx = r - 4608;
            W = proj_w + (size_t)l * FF * DD;
            Wt = base + OFF_PROJ;
            K = FF; N = DD; tn = idx % 24; tk = idx / 24;
        }
    } else {                                 // out_w [768,50257]
        int idx = bid - 6 * 6912;
        W = out_w;
        Wt = Wt_all + (size_t)6 * PL;
        K = DD; N = VV; tn = idx % 1571; tk = idx / 1571;
    }
    __shared__ float t[32][33];
    int bn = tn * 32, bk = tk * 32;
    int tx = threadIdx.x & 31, ty = threadIdx.x >> 5;
    for (int r = ty; r < 32; r += 8)
        t[r][tx] = (bn + tx < N) ? W[(size_t)(bk + r) * N + bn + tx] : 0.0f;
    __syncthreads();
    for (int r = ty; r < 32; r += 8) {
        int n = bn + r;
        if (n < N) Wt[(size_t)n * K + bk + tx] = __float2bfloat16(t[tx][r]);
    }
}

// LDS rows are 64B (32 bf16); 16B slots XOR-swizzled by ((row>>1)&3).
#define LDSOFF(row, ks) (((row) * 64) + ((((ks) ^ (((row) >> 1) & 3))) << 4))
// swizzled byte offset within a [rows][128B] LDS tile
#define SWZ128(row, byteoff) \
    ((row) * 128 + (((((byteoff) >> 4) ^ ((row) & 7)) & 7) << 4) + ((byteoff) & 15))

// XCD-grouped, M-fastest tile remap. nblk must be launched 1-D.
// Consecutive blocks on one XCD walk all M-tiles of one W-panel -> panel L2-resident.
__device__ __forceinline__ void tile_remap(int mtiles, int BM, int BN, int& bm, int& bn) {
    const int nblk = gridDim.x;
    int hw = blockIdx.x, j = hw;
    if ((nblk & 7) == 0) j = (hw & 7) * (nblk >> 3) + (hw >> 3);
    bm = (j % mtiles) * BM;
    bn = (j / mtiles) * BN;
}

// ---------------- generic bf16 MFMA GEMM ----------------
template<int BM, int BN>
__global__ __launch_bounds__(256) void gemm_mfma_kernel(
    const __hip_bfloat16* __restrict__ A, const __hip_bfloat16* __restrict__ Wt,
    const float* __restrict__ bias, const float* __restrict__ residual,
    float* __restrict__ Cf, __hip_bfloat16* __restrict__ Cb,
    int M, int N, int K, int do_gelu, int mtiles) {
    constexpr int BK = 32;
    constexpr int UA = (BM * 4) / 256;
    constexpr int UB = (BN * 4) / 256;
    constexpr int FM = BM / 32;
    constexpr int FN = BN / 32;
    __shared__ __align__(16) char As[BM * 64];
    __shared__ __align__(16) char Bs[BN * 64];

    const int tid = threadIdx.x;
    const int lane = tid & 63;
    const int wid = tid >> 6;
    int bm, bn;
    tile_remap(mtiles, BM, BN, bm, bn);
    const int r16 = lane & 15;
    const int kg = lane >> 4;
    const int wm = (wid >> 1) * (FM * 16);
    const int wn = (wid & 1) * (FN * 16);

    f32x4 acc[FM][FN];
    const f32x4 zf = {0.0f, 0.0f, 0.0f, 0.0f};
#pragma unroll
    for (int i = 0; i < FM; ++i)
#pragma unroll
        for (int j = 0; j < FN; ++j) acc[i][j] = zf;

    int4v areg[UA], breg[UB];
    const int4v zi = {0, 0, 0, 0};

#pragma unroll
    for (int u = 0; u < UA; ++u) {
        int c = tid + u * 256, row = c >> 2, sl = c & 3;
        areg[u] = *(const int4v*)(A + (size_t)(bm + row) * K + sl * 8);
    }
#pragma unroll
    for (int u = 0; u < UB; ++u) {
        int c = tid + u * 256, row = c >> 2, sl = c & 3;
        int4v bv = zi;
        if (bn + row < N) bv = *(const int4v*)(Wt + (size_t)(bn + row) * K + sl * 8);
        breg[u] = bv;
    }

    for (int k0 = 0; k0 < K; k0 += BK) {
        __syncthreads();
#pragma unroll
        for (int u = 0; u < UA; ++u) {
            int c = tid + u * 256, row = c >> 2, sl = c & 3;
            *(int4v*)(As + LDSOFF(row, sl)) = areg[u];
        }
#pragma unroll
        for (int u = 0; u < UB; ++u) {
            int c = tid + u * 256, row = c >> 2, sl = c & 3;
            *(int4v*)(Bs + LDSOFF(row, sl)) = breg[u];
        }
        __syncthreads();
        int kn = k0 + BK;
        if (kn < K) {
#pragma unroll
            for (int u = 0; u < UA; ++u) {
                int c = tid + u * 256, row = c >> 2, sl = c & 3;
                areg[u] = *(const int4v*)(A + (size_t)(bm + row) * K + kn + sl * 8);
            }
#pragma unroll
            for (int u = 0; u < UB; ++u) {
                int c = tid + u * 256, row = c >> 2, sl = c & 3;
                int4v bv = zi;
                if (bn + row < N) bv = *(const int4v*)(Wt + (size_t)(bn + row) * K + kn + sl * 8);
                breg[u] = bv;
            }
        }
        short8v af[FM], bfr[FN];
#pragma unroll
        for (int i = 0; i < FM; ++i) {
            int row = wm + i * 16 + r16;
            af[i] = *(const short8v*)(As + LDSOFF(row, kg));
        }
#pragma unroll
        for (int j = 0; j < FN; ++j) {
            int row = wn + j * 16 + r16;
            bfr[j] = *(const short8v*)(Bs + LDSOFF(row, kg));
        }
#pragma unroll
        for (int i = 0; i < FM; ++i)
#pragma unroll
            for (int j = 0; j < FN; ++j)
                acc[i][j] = __builtin_amdgcn_mfma_f32_16x16x32_bf16(
                    af[i], bfr[j], acc[i][j], 0, 0, 0);
    }

    const int rg = lane >> 4;
#pragma unroll
    for (int i = 0; i < FM; ++i) {
#pragma unroll
        for (int j = 0; j < FN; ++j) {
            int col = bn + wn + j * 16 + r16;
            if (col < N) {
#pragma unroll
                for (int r = 0; r < 4; ++r) {
                    int row = bm + wm + i * 16 + rg * 4 + r;
                    float v = acc[i][j][r];
                    if (bias) v += bias[col];
                    if (do_gelu) v = gelu_f(v);
                    size_t o = (size_t)row * N + col;
                    if (residual) v += residual[o];
                    if (Cf) Cf[o] = v;
                    else Cb[o] = __float2bfloat16(v);
                }
            }
        }
    }
}

// ---------------- QKV GEMM: xn @ [wq|wk|wv]^T -> Q(scaled), K, V^T ----------------
__global__ __launch_bounds__(256) void qkv_gemm_kernel(
    const __hip_bfloat16* __restrict__ A, const __hip_bfloat16* __restrict__ Wt,
    __hip_bfloat16* __restrict__ qh, __hip_bfloat16* __restrict__ kh,
    __hip_bfloat16* __restrict__ vt) {
    constexpr int BM = 128, BN = 128, BK = 32;
    constexpr int K = DD;
    constexpr int UA = 2, UB = 2, FM = 4, FN = 4;
    __shared__ __align__(16) char As[BM * 64];
    __shared__ __align__(16) char Bs[BN * 64];

    const int tid = threadIdx.x;
    const int lane = tid & 63;
    const int wid = tid >> 6;
    int bm, bn;
    tile_remap(16, BM, BN, bm, bn);
    const int r16 = lane & 15;
    const int kg = lane >> 4;
    const int wm = (wid >> 1) * 64;
    const int wn = (wid & 1) * 64;

    f32x4 acc[FM][FN];
    const f32x4 zf = {0.0f, 0.0f, 0.0f, 0.0f};
#pragma unroll
    for (int i = 0; i < FM; ++i)
#pragma unroll
        for (int j = 0; j < FN; ++j) acc[i][j] = zf;

    int4v areg[UA], breg[UB];
#pragma unroll
    for (int u = 0; u < UA; ++u) {
        int c = tid + u * 256, row = c >> 2, sl = c & 3;
        areg[u] = *(const int4v*)(A + (size_t)(bm + row) * K + sl * 8);
    }
#pragma unroll
    for (int u = 0; u < UB; ++u) {
        int c = tid + u * 256, row = c >> 2, sl = c & 3;
        breg[u] = *(const int4v*)(Wt + (size_t)(bn + row) * K + sl * 8);
    }

    for (int k0 = 0; k0 < K; k0 += BK) {
        __syncthreads();
#pragma unroll
        for (int u = 0; u < UA; ++u) {
            int c = tid + u * 256, row = c >> 2, sl = c & 3;
            *(int4v*)(As + LDSOFF(row, sl)) = areg[u];
        }
#pragma unroll
        for (int u = 0; u < UB; ++u) {
            int c = tid + u * 256, row = c >> 2, sl = c & 3;
            *(int4v*)(Bs + LDSOFF(row, sl)) = breg[u];
        }
        __syncthreads();
        int kn = k0 + BK;
        if (kn < K) {
#pragma unroll
            for (int u = 0; u < UA; ++u) {
                int c = tid + u * 256, row = c >> 2, sl = c & 3;
                areg[u] = *(const int4v*)(A + (size_t)(bm + row) * K + kn + sl * 8);
            }
#pragma unroll
            for (int u = 0; u < UB; ++u) {
                int c = tid + u * 256, row = c >> 2, sl = c & 3;
                breg[u] = *(const int4v*)(Wt + (size_t)(bn + row) * K + kn + sl * 8);
            }
        }
        short8v af[FM], bfr[FN];
#pragma unroll
        for (int i = 0; i < FM; ++i)
            af[i] = *(const short8v*)(As + LDSOFF(wm + i * 16 + r16, kg));
#pragma unroll
        for (int j = 0; j < FN; ++j)
            bfr[j] = *(const short8v*)(Bs + LDSOFF(wn + j * 16 + r16, kg));
#pragma unroll
        for (int i = 0; i < FM; ++i)
#pragma unroll
            for (int j = 0; j < FN; ++j)
                acc[i][j] = __builtin_amdgcn_mfma_f32_16x16x32_bf16(
                    af[i], bfr[j], acc[i][j], 0, 0, 0);
    }

#pragma unroll
    for (int i = 0; i < FM; ++i) {
#pragma unroll
        for (int j = 0; j < FN; ++j) {
            int col = bn + wn + j * 16 + r16;
#pragma unroll
            for (int r = 0; r < 4; ++r) {
                int row = bm + wm + i * 16 + kg * 4 + r;   // b*S + s
                int b = row >> 10, s = row & (SS - 1);
                float v = acc[i][j][r];
                if (col < DD) {
                    int h = col >> 6, d = col & 63;
                    qh[((size_t)(b * HH + h) * SS + s) * DKK + d] =
                        __float2bfloat16(v * 0.125f);       // fold 1/sqrt(64)
                } else if (col < 2 * DD) {
                    int c = col - DD, h = c >> 6, d = c & 63;
                    kh[((size_t)(b * HH + h) * SS + s) * DKK + d] = __float2bfloat16(v);
                } else {
                    int c = col - 2 * DD, h = c >> 6, d = c & 63;
                    vt[((size_t)(b * HH + h) * DKK + d) * SS + s] = __float2bfloat16(v);
                }
            }
        }
    }
}

// ---------------- flash attention: block = (b*h, q-tile of 64) ----------------
__global__ __launch_bounds__(256) void flash_attn_kernel(
    const __hip_bfloat16* __restrict__ qh, const __hip_bfloat16* __restrict__ kh,
    const __hip_bfloat16* __restrict__ vt, __hip_bfloat16* __restrict__ ctx) {
    __shared__ __align__(16) char Ks[KVBLK * 128];
    __shared__ __align__(16) char Vs[DKK * 128];
    __shared__ __align__(16) char Ps[4][16 * 128];

    const int bh = blockIdx.x;                       // 0..23
    const int qt = (gridDim.y - 1) - blockIdx.y;     // heavy tiles first
    const int q0 = qt * QBLK;
    const int b = bh / HH;
    const int h = bh - b * HH;
    const int tid = threadIdx.x;
    const int lane = tid & 63;
    const int w = tid >> 6;
    const int r16 = lane & 15;
    const int kg = lane >> 4;
    char* Pw = Ps[w];

    const size_t qbase = ((size_t)bh * SS + q0 + w * 16 + r16) * DKK;
    short8v qf0 = *(const short8v*)(qh + qbase + kg * 8);
    short8v qf1 = *(const short8v*)(qh + qbase + 32 + kg * 8);

    f32x4 acc_o[4];
    const f32x4 zf = {0.0f, 0.0f, 0.0f, 0.0f};
    float m[4], l[4];
#pragma unroll
    for (int j = 0; j < 4; ++j) acc_o[j] = zf;
#pragma unroll
    for (int r = 0; r < 4; ++r) { m[r] = -1e30f; l[r] = 0.0f; }

    const int nt = qt + 1;
    for (int t = 0; t < nt; ++t) {
        __syncthreads();
        {
            const __hip_bfloat16* kp = kh + ((size_t)bh * SS + t * KVBLK) * DKK;
            const __hip_bfloat16* vp = vt + (size_t)bh * DKK * SS + t * KVBLK;
#pragma unroll
            for (int u = 0; u < 2; ++u) {
                int c = tid + u * 256;              // 0..511
                int row = c >> 3, slot = c & 7;
                *(int4v*)(Ks + SWZ128(row, slot * 16)) =
                    *(const int4v*)(kp + (size_t)row * DKK + slot * 8);
                *(int4v*)(Vs + SWZ128(row, slot * 16)) =
                    *(const int4v*)(vp + (size_t)row * SS + slot * 8);
            }
        }
        __syncthreads();

        f32x4 s[4];
#pragma unroll
        for (int j = 0; j < 4; ++j) s[j] = zf;
#pragma unroll
        for (int j = 0; j < 4; ++j) {
            short8v k0f = *(const short8v*)(Ks + SWZ128(j * 16 + r16, kg * 16));
            short8v k1f = *(const short8v*)(Ks + SWZ128(j * 16 + r16, 64 + kg * 16));
            s[j] = __builtin_amdgcn_mfma_f32_16x16x32_bf16(qf0, k0f, s[j], 0, 0, 0);
            s[j] = __builtin_amdgcn_mfma_f32_16x16x32_bf16(qf1, k1f, s[j], 0, 0, 0);
        }

        if (t == qt) {
#pragma unroll
            for (int j = 0; j < 4; ++j)
#pragma unroll
                for (int r = 0; r < 4; ++r)
                    if (j * 16 + r16 > w * 16 + kg * 4 + r) s[j][r] = -1e30f;
        }

        float alpha[4], rsum[4];
#pragma unroll
        for (int r = 0; r < 4; ++r) {
            float v = fmaxf(fmaxf(s[0][r], s[1][r]), fmaxf(s[2][r], s[3][r]));
#pragma unroll
            for (int d2 = 1; d2 < 16; d2 <<= 1)
                v = fmaxf(v, __shfl_xor(v, d2));
            float mnew = fmaxf(m[r], v);
            alpha[r] = __expf(m[r] - mnew);
            m[r] = mnew;
            rsum[r] = 0.0f;
        }
#pragma unroll
        for (int j = 0; j < 4; ++j)
#pragma unroll
            for (int r = 0; r < 4; ++r) {
                float p = __expf(s[j][r] - m[r]);
                rsum[r] += p;
                *(__hip_bfloat16*)(Pw + SWZ128(kg * 4 + r, (j * 16 + r16) * 2)) =
                    __float2bfloat16(p);
            }
#pragma unroll
        for (int r = 0; r < 4; ++r) {
#pragma unroll
            for (int d2 = 1; d2 < 16; d2 <<= 1)
                rsum[r] += __shfl_xor(rsum[r], d2);
            l[r] = l[r] * alpha[r] + rsum[r];
        }
#pragma unroll
        for (int j = 0; j < 4; ++j)
#pragma unroll
            for (int r = 0; r < 4; ++r) acc_o[j][r] *= alpha[r];

        short8v pa0 = *(const short8v*)(Pw + SWZ128(r16, kg * 16));
        short8v pa1 = *(const short8v*)(Pw + SWZ128(r16, 64 + kg * 16));
#pragma unroll
        for (int j = 0; j < 4; ++j) {
            short8v v0f = *(const short8v*)(Vs + SWZ128(j * 16 + r16, kg * 16));
            short8v v1f = *(const short8v*)(Vs + SWZ128(j * 16 + r16, 64 + kg * 16));
            acc_o[j] = __builtin_amdgcn_mfma_f32_16x16x32_bf16(pa0, v0f, acc_o[j], 0, 0, 0);
            acc_o[j] = __builtin_amdgcn_mfma_f32_16x16x32_bf16(pa1, v1f, acc_o[j], 0, 0, 0);
        }
    }

#pragma unroll
    for (int r = 0; r < 4; ++r) {
        float inv = 1.0f / l[r];
        int row = q0 + w * 16 + kg * 4 + r;
        __hip_bfloat16* cp = ctx + ((size_t)(b * SS) + row) * DD + h * DKK;
#pragma unroll
        for (int j = 0; j < 4; ++j)
            cp[j * 16 + r16] = __float2bfloat16(acc_o[j][r] * inv);
    }
}

// ---------------- fp32 fallback GEMM / attention ----------------
__global__ __launch_bounds__(256) void gemm_kernel(
    const float* __restrict__ A, const float* __restrict__ W,
    const float* __restrict__ bias, const float* __restrict__ residual,
    float* __restrict__ C, int M, int N, int K, int do_gelu) {
    __shared__ float As[16][64];
    __shared__ float Ws[16][68];
    int tid = threadIdx.x;
    int bn = blockIdx.x * 64, bm = blockIdx.y * 64;
    int tx = tid & 15, ty = tid >> 4;
    int ar = tid >> 2, ak = (tid & 3) << 2;
    int wr = tid >> 4, wc = (tid & 15) << 2;
    bool n_vec = ((N & 3) == 0);
    float acc[4][4] = {};
    for (int k0 = 0; k0 < K; k0 += 16) {
        float4 av = *(const float4*)&A[(size_t)(bm + ar) * K + (k0 + ak)];
        As[ak + 0][ar] = av.x; As[ak + 1][ar] = av.y;
        As[ak + 2][ar] = av.z; As[ak + 3][ar] = av.w;
        int gn = bn + wc;
        const float* wp = &W[(size_t)(k0 + wr) * N + gn];
        float w0, w1, w2, w3;
        if (n_vec && gn + 3 < N) {
            float4 wv4 = *(const float4*)wp;
            w0 = wv4.x; w1 = wv4.y; w2 = wv4.z; w3 = wv4.w;
        } else {
            w0 = (gn + 0 < N) ? wp[0] : 0.0f;
            w1 = (gn + 1 < N) ? wp[1] : 0.0f;
            w2 = (gn + 2 < N) ? wp[2] : 0.0f;
            w3 = (gn + 3 < N) ? wp[3] : 0.0f;
        }
        Ws[wr][wc + 0] = w0; Ws[wr][wc + 1] = w1;
        Ws[wr][wc + 2] = w2; Ws[wr][wc + 3] = w3;
        __syncthreads();
#pragma unroll
        for (int kk = 0; kk < 16; ++kk) {
            float a[4], w[4];
#pragma unroll
            for (int i = 0; i < 4; ++i) a[i] = As[kk][ty * 4 + i];
#pragma unroll
            for (int j = 0; j < 4; ++j) w[j] = Ws[kk][tx * 4 + j];
#pragma unroll
            for (int i = 0; i < 4; ++i)
#pragma unroll
                for (int j = 0; j < 4; ++j)
                    acc[i][j] = fmaf(a[i], w[j], acc[i][j]);
        }
        __syncthreads();
    }
#pragma unroll
    for (int i = 0; i < 4; ++i) {
        int row = bm + ty * 4 + i;
#pragma unroll
        for (int j = 0; j < 4; ++j) {
            int col = bn + tx * 4 + j;
            if (col < N) {
                float val = acc[i][j];
                if (bias) val += bias[col];
                if (do_gelu) val = gelu_f(val);
                if (residual) val += residual[(size_t)row * N + col];
                C[(size_t)row * N + col] = val;
            }
        }
    }
}

__global__ __launch_bounds__(256) void attn_kernel(
    const float* __restrict__ q, const float* __restrict__ k,
    const float* __restrict__ v, float* __restrict__ ctx) {
    int bid = blockIdx.x;
    int qi = bid & (SS - 1);
    int bh = bid >> 10;
    int h = bh % HH;
    int b = bh / HH;
    int tid = threadIdx.x;
    __shared__ float qs[DKK];
    __shared__ float p[SS];
    __shared__ float red[256];
    __shared__ float ctx_red[4][DKK];
    const float* qrow = q + ((size_t)(b * SS + qi)) * DD + h * DKK;
    if (tid < DKK) qs[tid] = qrow[tid];
    __syncthreads();
    int nk = qi + 1;
    const float scale = 0.125f;
    for (int ki = tid; ki < nk; ki += 256) {
        const float* krow = k + ((size_t)(b * SS + ki)) * DD + h * DKK;
        float dot = 0.0f;
#pragma unroll
        for (int d = 0; d < DKK; d += 4) {
            float4 kv = *(const float4*)&krow[d];
            dot += qs[d] * kv.x + qs[d + 1] * kv.y + qs[d + 2] * kv.z + qs[d + 3] * kv.w;
        }
        p[ki] = dot * scale;
    }
    __syncthreads();
    float lmax = -1e30f;
    for (int ki = tid; ki < nk; ki += 256) lmax = fmaxf(lmax, p[ki]);
    red[tid] = lmax;
    __syncthreads();
    for (int s2 = 128; s2 > 0; s2 >>= 1) {
        if (tid < s2) red[tid] = fmaxf(red[tid], red[tid + s2]);
        __syncthreads();
    }
    float mm = red[0];
    __syncthreads();
    float lsum = 0.0f;
    for (int ki = tid; ki < nk; ki += 256) {
        float e = __expf(p[ki] - mm);
        p[ki] = e;
        lsum += e;
    }
    red[tid] = lsum;
    __syncthreads();
    for (int s2 = 128; s2 > 0; s2 >>= 1) {
        if (tid < s2) red[tid] += red[tid + s2];
        __syncthreads();
    }
    float inv = 1.0f / red[0];
    int d = tid & 63;
    int chunk = tid >> 6;
    float accd = 0.0f;
    for (int ki = chunk; ki < nk; ki += 4)
        accd += p[ki] * v[((size_t)(b * SS + ki)) * DD + h * DKK + d];
    ctx_red[chunk][d] = accd;
    __syncthreads();
    if (tid < DKK) {
        float sum = (ctx_red[0][tid] + ctx_red[1][tid]) + (ctx_red[2][tid] + ctx_red[3][tid]);
        ctx[((size_t)(b * SS + qi)) * DD + h * DKK + tid] = sum * inv;
    }
}

// ---------------- host-side orchestration ----------------
extern "C" void kernel_launch(void* const* d_in, const int* in_sizes, int n_in,
                              void* d_out, int out_size, void* d_ws, size_t ws_size,
                              hipStream_t stream) {
    const int*   ids    = (const int*)  d_in[0];
    const float* tok    = (const float*)d_in[1];
    const float* pos    = (const float*)d_in[2];
    const float* wq     = (const float*)d_in[3];
    const float* wk     = (const float*)d_in[4];
    const float* wv     = (const float*)d_in[5];
    const float* wo     = (const float*)d_in[6];
    const float* bo     = (const float*)d_in[7];
    const float* fc_w   = (const float*)d_in[8];
    const float* fc_b   = (const float*)d_in[9];
    const float* proj_w = (const float*)d_in[10];
    const float* proj_b = (const float*)d_in[11];
    const float* ln1_g  = (const float*)d_in[12];
    const float* ln1_b  = (const float*)d_in[13];
    const float* ln2_g  = (const float*)d_in[14];
    const float* ln2_b  = (const float*)d_in[15];
    const float* lnf_g  = (const float*)d_in[16];
    const float* lnf_b  = (const float*)d_in[17];
    const float* out_w  = (const float*)d_in[18];
    float* out = (float*)d_out;

    dim3 blk(256);

    const size_t SZ_X    = (size_t)NROWS * DD * 4;
    const size_t SZ_XN   = (size_t)NROWS * DD * 2;
    const size_t SZ_HD   = (size_t)BB * HH * SS * DKK * 2;
    const size_t SZ_CTX  = (size_t)NROWS * DD * 2;
    const size_t SZ_H    = (size_t)NROWS * FF * 2;
    const size_t SZ_WT1  = (size_t)50304 * DD * 2;             // shared (mid)
    const size_t SZ_WTA  = ((size_t)6 * PL + (size_t)50304 * DD) * 2;  // all (big)
    const size_t ACT     = SZ_X + SZ_XN + 3 * SZ_HD + SZ_CTX + SZ_H;
    const size_t NEED_MID = ACT + SZ_WT1;
    const size_t NEED_BIG = ACT + SZ_WTA;

    if (ws_size >= NEED_MID) {
        const bool big = (ws_size >= NEED_BIG);
        char* p = (char*)d_ws;
        float*          x    = (float*)p;          p += SZ_X;
        __hip_bfloat16* xn   = (__hip_bfloat16*)p; p += SZ_XN;
        __hip_bfloat16* qhb  = (__hip_bfloat16*)p; p += SZ_HD;
        __hip_bfloat16* khb  = (__hip_bfloat16*)p; p += SZ_HD;
        __hip_bfloat16* vtb  = (__hip_bfloat16*)p; p += SZ_HD;
        __hip_bfloat16* ctx  = (__hip_bfloat16*)p; p += SZ_CTX;
        __hip_bfloat16* hbuf = (__hip_bfloat16*)p; p += SZ_H;
        __hip_bfloat16* Wt   = (__hip_bfloat16*)p;

        dim3 tD(DD / 32, DD / 32);
        dim3 tF(FF / 32, DD / 32);
        dim3 tP(DD / 32, FF / 32);
        dim3 tV((VV + 31) / 32, DD / 32);

        const int nQKV = (QKVN / 128) * (NROWS / 128);         // 288
        const int nFC  = (FF / 128) * (NROWS / 128);           // 384
        const int nWO  = (DD / 64) * (NROWS / 64);             // 384
        const int nV   = ((VV + 127) / 128) * (NROWS / 128);   // 6288
        dim3 gA(BB * HH, SS / QBLK);                           // 24 x 16

        if (big)
            transpose_all_kernel<<<6 * 6912 + 37704, blk, 0, stream>>>(
                wq, wk, wv, wo, fc_w, proj_w, out_w, Wt);

        embed_kernel<<<NROWS, blk, 0, stream>>>(ids, tok, pos, x);

        for (int l = 0; l < LL; ++l) {
            __hip_bfloat16* qkvWt = big ? Wt + (size_t)l * PL : Wt;
            __hip_bfloat16* woWt  = big ? Wt + (size_t)l * PL + OFF_WO : Wt;
            __hip_bfloat16* fcWt  = big ? Wt + (size_t)l * PL + OFF_FC : Wt;
            __hip_bfloat16* pjWt  = big ? Wt + (size_t)l * PL + OFF_PROJ : Wt;

            ln_bf16_kernel<<<NROWS, blk, 0, stream>>>(x, ln1_g + l * DD, ln1_b + l * DD, xn);
            if (!big) {
                transpose_cvt_kernel<<<tD, blk, 0, stream>>>(wq + (size_t)l * DD * DD, qkvWt, DD, DD);
                transpose_cvt_kernel<<<tD, blk, 0, stream>>>(wk + (size_t)l * DD * DD, qkvWt + (size_t)DD * DD, DD, DD);
                transpose_cvt_kernel<<<tD, blk, 0, stream>>>(wv + (size_t)l * DD * DD, qkvWt + (size_t)2 * DD * DD, DD, DD);
            }
            qkv_gemm_kernel<<<nQKV, blk, 0, stream>>>(xn, qkvWt, qhb, khb, vtb);
            flash_attn_kernel<<<gA, blk, 0, stream>>>(qhb, khb, vtb, ctx);
            if (!big)
                transpose_cvt_kernel<<<tD, blk, 0, stream>>>(wo + (size_t)l * DD * DD, woWt, DD, DD);
            gemm_mfma_kernel<64, 64><<<nWO, blk, 0, stream>>>(
                ctx, woWt, bo + l * DD, x, x, nullptr, NROWS, DD, DD, 0, NROWS / 64);
            ln_bf16_kernel<<<NROWS, blk, 0, stream>>>(x, ln2_g + l * DD, ln2_b + l * DD, xn);
            if (!big)
                transpose_cvt_kernel<<<tF, blk, 0, stream>>>(fc_w + (size_t)l * DD * FF, fcWt, DD, FF);
            gemm_mfma_kernel<128, 128><<<nFC, blk, 0, stream>>>(
                xn, fcWt, fc_b + l * FF, nullptr, nullptr, hbuf, NROWS, FF, DD, 1, NROWS / 128);
            if (!big)
                transpose_cvt_kernel<<<tP, blk, 0, stream>>>(proj_w + (size_t)l * FF * DD, pjWt, FF, DD);
            gemm_mfma_kernel<64, 64><<<nWO, blk, 0, stream>>>(
                hbuf, pjWt, proj_b + l * DD, x, x, nullptr, NROWS, DD, FF, 0, NROWS / 64);
        }

        __hip_bfloat16* outWt = big ? Wt + (size_t)6 * PL : Wt;
        ln_bf16_kernel<<<NROWS, blk, 0, stream>>>(x, lnf_g, lnf_b, xn);
        if (!big)
            transpose_cvt_kernel<<<tV, blk, 0, stream>>>(out_w, outWt, DD, VV);
        gemm_mfma_kernel<128, 128><<<nV, blk, 0, stream>>>(
            xn, outWt, nullptr, nullptr, out, nullptr, NROWS, VV, DD, 0, NROWS / 128);
        return;
    }

    // ---- fallback: proven fp32 path ----
    const size_t XSZ = (size_t)NROWS * DD;
    float* ws = (float*)d_ws;
    float* x  = ws;
    float* xn = x  + XSZ;
    float* qb = xn + XSZ;
    float* kb = qb + XSZ;
    float* vb = kb + XSZ;
    float* cb = vb + XSZ;
    float* hb = cb + XSZ;

    dim3 gD((DD + 63) / 64, NROWS / 64);
    dim3 gF((FF + 63) / 64, NROWS / 64);
    dim3 gV2((VV + 63) / 64, NROWS / 64);

    embed_kernel<<<NROWS, blk, 0, stream>>>(ids, tok, pos, x);
    for (int l = 0; l < LL; ++l) {
        const float* wq_l = wq + (size_t)l * DD * DD;
        const float* wk_l = wk + (size_t)l * DD * DD;
        const float* wv_l = wv + (size_t)l * DD * DD;
        const float* wo_l = wo + (size_t)l * DD * DD;
        const float* fc_w_l = fc_w + (size_t)l * DD * FF;
        const float* pj_w_l = proj_w + (size_t)l * FF * DD;
        ln_kernel<<<NROWS, blk, 0, stream>>>(x, ln1_g + l * DD, ln1_b + l * DD, xn);
        gemm_kernel<<<gD, blk, 0, stream>>>(xn, wq_l, nullptr, nullptr, qb, NROWS, DD, DD, 0);
        gemm_kernel<<<gD, blk, 0, stream>>>(xn, wk_l, nullptr, nullptr, kb, NROWS, DD, DD, 0);
        gemm_kernel<<<gD, blk, 0, stream>>>(xn, wv_l, nullptr, nullptr, vb, NROWS, DD, DD, 0);
        attn_kernel<<<BB * HH * SS, blk, 0, stream>>>(qb, kb, vb, cb);
        gemm_kernel<<<gD, blk, 0, stream>>>(cb, wo_l, bo + l * DD, x, x, NROWS, DD, DD, 0);
        ln_kernel<<<NROWS, blk, 0, stream>>>(x, ln2_g + l * DD, ln2_b + l * DD, xn);
        gemm_kernel<<<gF, blk, 0, stream>>>(xn, fc_w_l, fc_b + l * FF, nullptr, hb, NROWS, FF, DD, 1);
        gemm_kernel<<<gD, blk, 0, stream>>>(hb, pj_w_l, proj_b + l * DD, x, x, NROWS, DD, FF, 0);
    }
    ln_kernel<<<NROWS, blk, 0, stream>>>(x, lnf_g, lnf_b, xn);
    gemm_kernel<<<gV2, blk, 0, stream>>>(xn, out_w, nullptr, nullptr, out, NROWS, VV, DD, 0);
}